// Round 2
// baseline (1144.117 us; speedup 1.0000x reference)
//
#include <hip/hip_runtime.h>
#include <math.h>

namespace {

constexpr int NF   = 256;   // n_feature / tokens
constexpr int EH   = 128;   // embedder hidden
constexpr int E    = 64;    // embedded dim
constexpr int H    = 64;    // lstm size
constexpr int SHD  = 256;   // shared hidden
constexpr int SD   = 128;   // shared dim
constexpr int NA   = 257;   // n_action
constexpr int NSHUF = 4;

__device__ __forceinline__ float fsig(float x) {   // saturating-safe sigmoid
  return 1.f / (1.f + __expf(-x));
}
__device__ __forceinline__ float ftanh(float x) {  // saturating-safe tanh
  return 1.f - 2.f / (__expf(2.f * x) + 1.f);
}

__global__ __launch_bounds__(256, 4) void seqnet(
    const float* __restrict__ state, const int* __restrict__ acquired,
    const float* __restrict__ We1, const float* __restrict__ be1,
    const float* __restrict__ We2, const float* __restrict__ be2,
    const float* __restrict__ Wih, const float* __restrict__ Whh,
    const float* __restrict__ bih, const float* __restrict__ bhh,
    const float* __restrict__ Ws1, const float* __restrict__ bs1,
    const float* __restrict__ Ws2, const float* __restrict__ bs2,
    const float* __restrict__ Wp1, const float* __restrict__ bp1,
    const float* __restrict__ Wp2, const float* __restrict__ bp2,
    const float* __restrict__ Wv1, const float* __restrict__ bv1,
    const float* __restrict__ Wv2, const float* __restrict__ bv2,
    float* __restrict__ out)
{
  const int b    = blockIdx.x;
  const int t    = threadIdx.x;
  const int lane = t & 63;
  const int wid  = t >> 6;

  __shared__ int   id_l[NF];
  __shared__ float val_l[NF];
  __shared__ int   wcnt[4];
  __shared__ float wmax[4];
  __shared__ float wsum[4];
  __shared__ float qt_s[H];
  __shared__ float ct_s[H];
  __shared__ float att_s[E];
  __shared__ float gates_s[4 * H];
  __shared__ float part[4][E];
  __shared__ float t1_s[SHD];
  __shared__ float sh_s[SD];
  __shared__ float a1_s[SD];
  __shared__ float v1_s[SD];
  __shared__ float v_scalar;

  // ---------------- phase 0: closed-form "argsort" ----------------
  const int ai = (acquired[b * NF + t] != 0) ? 1 : 0;
  const unsigned long long mask = __ballot(ai);
  const int pin = __popcll(mask & ((1ull << lane) - 1ull));
  if (lane == 0) wcnt[wid] = __popcll(mask);
  if (t < H) { qt_s[t] = 0.f; ct_s[t] = 0.f; att_s[t] = 0.f; }
  __syncthreads();
  int pexcl = pin;
  int L = 0;
  #pragma unroll
  for (int w = 0; w < 4; ++w) {
    const int c = wcnt[w];
    if (w < wid) pexcl += c;
    L += c;
  }
  if (ai) {
    const int rank = L - pexcl - 1;      // # acquired with index > t
    id_l[rank]  = t + 1;
    val_l[rank] = state[b * NF + t];
  }
  __syncthreads();

  // ---------------- phase 1: embedder (thread t == token t) ----------------
  float emb[E];
  #pragma unroll
  for (int e = 0; e < E; ++e) emb[e] = 0.f;
  if (t < L) {
    const int   id = id_l[t];
    const float v  = val_l[t];
    const float* __restrict__ w1r = We1 + id * EH;
    for (int k = 0; k < EH; k += 4) {
      const float4 wr = *(const float4*)(w1r + k);        // per-lane gather
      const float4 w0 = *(const float4*)(We1 + k);        // uniform
      const float4 bb = *(const float4*)(be1 + k);        // uniform
      const float h0 = fmaxf(fmaf(v, w0.x, wr.x) + bb.x, 0.f);
      const float h1 = fmaxf(fmaf(v, w0.y, wr.y) + bb.y, 0.f);
      const float h2 = fmaxf(fmaf(v, w0.z, wr.z) + bb.z, 0.f);
      const float h3 = fmaxf(fmaf(v, w0.w, wr.w) + bb.w, 0.f);
      const float* __restrict__ w2r = We2 + k * E;        // uniform rows
      #pragma unroll
      for (int e = 0; e < E; e += 4) {
        const float4 r0 = *(const float4*)(w2r + e);
        const float4 r1 = *(const float4*)(w2r + E + e);
        const float4 r2 = *(const float4*)(w2r + 2 * E + e);
        const float4 r3 = *(const float4*)(w2r + 3 * E + e);
        emb[e]   = fmaf(h3, r3.x, fmaf(h2, r2.x, fmaf(h1, r1.x, fmaf(h0, r0.x, emb[e]))));
        emb[e+1] = fmaf(h3, r3.y, fmaf(h2, r2.y, fmaf(h1, r1.y, fmaf(h0, r0.y, emb[e+1]))));
        emb[e+2] = fmaf(h3, r3.z, fmaf(h2, r2.z, fmaf(h1, r1.z, fmaf(h0, r0.z, emb[e+2]))));
        emb[e+3] = fmaf(h3, r3.w, fmaf(h2, r2.w, fmaf(h1, r1.w, fmaf(h0, r0.w, emb[e+3]))));
      }
    }
    #pragma unroll
    for (int e = 0; e < E; ++e) emb[e] += be2[e];
  }

  // ---------------- phase 2: attention + LSTM ----------------
  if (L > 0) {
    const float invL = 1.f / (float)L;
    for (int it = 0; it < NSHUF; ++it) {
      float w;
      if (it == 0) {
        // qt == 0 -> logits 0 (masked) -> uniform softmax over first L tokens
        w = (t < L) ? invL : 0.f;
      } else {
        float a0 = 0.f, a1 = 0.f, a2 = 0.f, a3 = 0.f;
        #pragma unroll
        for (int e = 0; e < E; e += 4) {
          const float4 q = *(const float4*)(qt_s + e);
          a0 = fmaf(emb[e],     q.x, a0);
          a1 = fmaf(emb[e + 1], q.y, a1);
          a2 = fmaf(emb[e + 2], q.z, a2);
          a3 = fmaf(emb[e + 3], q.w, a3);
        }
        const float lg = (t < L) ? (a0 + a1) + (a2 + a3) : -1e30f;
        float m = lg;
        #pragma unroll
        for (int d = 32; d > 0; d >>= 1) m = fmaxf(m, __shfl_xor(m, d));
        if (lane == 0) wmax[wid] = m;
        __syncthreads();
        m = fmaxf(fmaxf(wmax[0], wmax[1]), fmaxf(wmax[2], wmax[3]));
        const float p = (t < L) ? __expf(lg - m) : 0.f;
        float s = p;
        #pragma unroll
        for (int d = 32; d > 0; d >>= 1) s += __shfl_xor(s, d);
        if (lane == 0) wsum[wid] = s;
        __syncthreads();
        s = (wsum[0] + wsum[1]) + (wsum[2] + wsum[3]);
        w = p / s;
      }

      // attended[e] = sum_t w_t * emb_t[e] — chunked (16-col) butterfly
      #pragma unroll
      for (int c = 0; c < 4; ++c) {
        float u[16];
        #pragma unroll
        for (int j = 0; j < 16; ++j) u[j] = w * emb[c * 16 + j];
        #pragma unroll
        for (int j = 0; j < 16; ++j) u[j] += __shfl_xor(u[j], 32);
        #pragma unroll
        for (int j = 0; j < 16; ++j) u[j] += __shfl_xor(u[j], 16);
        #pragma unroll
        for (int step = 0; step < 4; ++step) {
          const int d = 8 >> step;
          const bool hi = (lane & d) != 0;
          #pragma unroll
          for (int i = 0; i < d; ++i) {
            const float keep = hi ? u[i + d] : u[i];
            const float send = hi ? u[i] : u[i + d];
            u[i] = keep + __shfl_xor(send, d);
          }
        }
        if (lane < 16) part[wid][c * 16 + lane] = u[0];
      }
      __syncthreads();
      if (t < E) att_s[t] = (part[0][t] + part[1][t]) + (part[2][t] + part[3][t]);
      __syncthreads();

      // gates[t] = att @ Wih[:,t] (+ qt @ Whh[:,t]) + bih[t] + bhh[t]
      float g0 = 0.f, g1 = 0.f, g2 = 0.f, g3 = 0.f;
      for (int e = 0; e < E; e += 4) {
        const float4 a = *(const float4*)(att_s + e);
        g0 = fmaf(a.x, Wih[(e)     * (4 * H) + t], g0);
        g1 = fmaf(a.y, Wih[(e + 1) * (4 * H) + t], g1);
        g2 = fmaf(a.z, Wih[(e + 2) * (4 * H) + t], g2);
        g3 = fmaf(a.w, Wih[(e + 3) * (4 * H) + t], g3);
      }
      if (it > 0) {
        for (int h = 0; h < H; h += 4) {
          const float4 q = *(const float4*)(qt_s + h);
          g0 = fmaf(q.x, Whh[(h)     * (4 * H) + t], g0);
          g1 = fmaf(q.y, Whh[(h + 1) * (4 * H) + t], g1);
          g2 = fmaf(q.z, Whh[(h + 2) * (4 * H) + t], g2);
          g3 = fmaf(q.w, Whh[(h + 3) * (4 * H) + t], g3);
        }
      }
      gates_s[t] = bih[t] + bhh[t] + (g0 + g1) + (g2 + g3);
      __syncthreads();
      if (t < H) {
        const float ig = gates_s[t];
        const float fg = gates_s[H + t];
        const float gg = gates_s[2 * H + t];
        const float og = gates_s[3 * H + t];
        float c = ct_s[t];
        c = fsig(fg) * c + fsig(ig) * ftanh(gg);
        ct_s[t] = c;
        qt_s[t] = fsig(og) * ftanh(c);
      }
      __syncthreads();
    }
  }

  // ---------------- phase 3: DuelingNet ----------------
  {
    float x0 = 0.f, x1 = 0.f, x2 = 0.f, x3 = 0.f;
    for (int k = 0; k < E; k += 4) {
      const float4 a = *(const float4*)(att_s + k);
      x0 = fmaf(a.x, Ws1[(k)     * SHD + t], x0);
      x1 = fmaf(a.y, Ws1[(k + 1) * SHD + t], x1);
      x2 = fmaf(a.z, Ws1[(k + 2) * SHD + t], x2);
      x3 = fmaf(a.w, Ws1[(k + 3) * SHD + t], x3);
    }
    for (int k = 0; k < H; k += 4) {
      const float4 q = *(const float4*)(qt_s + k);
      x0 = fmaf(q.x, Ws1[(E + k)     * SHD + t], x0);
      x1 = fmaf(q.y, Ws1[(E + k + 1) * SHD + t], x1);
      x2 = fmaf(q.z, Ws1[(E + k + 2) * SHD + t], x2);
      x3 = fmaf(q.w, Ws1[(E + k + 3) * SHD + t], x3);
    }
    t1_s[t] = fmaxf(bs1[t] + (x0 + x1) + (x2 + x3), 0.f);
  }
  __syncthreads();
  if (t < SD) {
    float x0 = 0.f, x1 = 0.f, x2 = 0.f, x3 = 0.f;
    for (int k = 0; k < SHD; k += 4) {
      const float4 a = *(const float4*)(t1_s + k);
      x0 = fmaf(a.x, Ws2[(k)     * SD + t], x0);
      x1 = fmaf(a.y, Ws2[(k + 1) * SD + t], x1);
      x2 = fmaf(a.z, Ws2[(k + 2) * SD + t], x2);
      x3 = fmaf(a.w, Ws2[(k + 3) * SD + t], x3);
    }
    sh_s[t] = fmaxf(bs2[t] + (x0 + x1) + (x2 + x3), 0.f);
  }
  __syncthreads();
  if (t < SD) {
    float x0 = 0.f, x1 = 0.f, x2 = 0.f, x3 = 0.f;
    for (int k = 0; k < SD; k += 4) {
      const float4 a = *(const float4*)(sh_s + k);
      x0 = fmaf(a.x, Wp1[(k)     * SD + t], x0);
      x1 = fmaf(a.y, Wp1[(k + 1) * SD + t], x1);
      x2 = fmaf(a.z, Wp1[(k + 2) * SD + t], x2);
      x3 = fmaf(a.w, Wp1[(k + 3) * SD + t], x3);
    }
    a1_s[t] = fmaxf(bp1[t] + (x0 + x1) + (x2 + x3), 0.f);
  } else {
    const int tt = t - SD;
    float x0 = 0.f, x1 = 0.f, x2 = 0.f, x3 = 0.f;
    for (int k = 0; k < SD; k += 4) {
      const float4 a = *(const float4*)(sh_s + k);
      x0 = fmaf(a.x, Wv1[(k)     * SD + tt], x0);
      x1 = fmaf(a.y, Wv1[(k + 1) * SD + tt], x1);
      x2 = fmaf(a.z, Wv1[(k + 2) * SD + tt], x2);
      x3 = fmaf(a.w, Wv1[(k + 3) * SD + tt], x3);
    }
    v1_s[tt] = fmaxf(bv1[tt] + (x0 + x1) + (x2 + x3), 0.f);
  }
  __syncthreads();
  if (wid == 1) {   // v = v1 @ Wv2 + bv2 (wave 1; wave 0 has the adv2 extra column)
    float vv = fmaf(v1_s[lane], Wv2[lane], v1_s[lane + 64] * Wv2[lane + 64]);
    #pragma unroll
    for (int d = 32; d > 0; d >>= 1) vv += __shfl_xor(vv, d);
    if (lane == 0) v_scalar = vv + bv2[0];
  }
  // adv: one column per thread (+ col 256 on thread 0)
  float x0 = 0.f, x1 = 0.f, x2 = 0.f, x3 = 0.f;
  for (int k = 0; k < SD; k += 4) {
    const float4 a = *(const float4*)(a1_s + k);
    x0 = fmaf(a.x, Wp2[(k)     * NA + t], x0);
    x1 = fmaf(a.y, Wp2[(k + 1) * NA + t], x1);
    x2 = fmaf(a.z, Wp2[(k + 2) * NA + t], x2);
    x3 = fmaf(a.w, Wp2[(k + 3) * NA + t], x3);
  }
  const float adv = bp2[t] + (x0 + x1) + (x2 + x3);
  float adv2 = 0.f;
  if (t == 0) {
    float y0 = 0.f, y1 = 0.f, y2 = 0.f, y3 = 0.f;
    for (int k = 0; k < SD; k += 4) {
      const float4 a = *(const float4*)(a1_s + k);
      y0 = fmaf(a.x, Wp2[(k)     * NA + (NA - 1)], y0);
      y1 = fmaf(a.y, Wp2[(k + 1) * NA + (NA - 1)], y1);
      y2 = fmaf(a.z, Wp2[(k + 2) * NA + (NA - 1)], y2);
      y3 = fmaf(a.w, Wp2[(k + 3) * NA + (NA - 1)], y3);
    }
    adv2 = bp2[NA - 1] + (y0 + y1) + (y2 + y3);
  }
  float ssum = adv + adv2;
  #pragma unroll
  for (int d = 32; d > 0; d >>= 1) ssum += __shfl_xor(ssum, d);
  if (lane == 0) wsum[wid] = ssum;
  __syncthreads();
  const float mean = ((wsum[0] + wsum[1]) + (wsum[2] + wsum[3])) * (1.f / (float)NA);
  const float vv = v_scalar;
  out[b * NA + t] = vv + adv - mean;
  if (t == 0) out[b * NA + (NA - 1)] = vv + adv2 - mean;
}

}  // namespace

extern "C" void kernel_launch(void* const* d_in, const int* in_sizes, int n_in,
                              void* d_out, int out_size, void* d_ws, size_t ws_size,
                              hipStream_t stream) {
  const float* state    = (const float*)d_in[0];
  const int*   acquired = (const int*)d_in[1];
  const float* We1 = (const float*)d_in[2];
  const float* be1 = (const float*)d_in[3];
  const float* We2 = (const float*)d_in[4];
  const float* be2 = (const float*)d_in[5];
  const float* Wih = (const float*)d_in[6];
  const float* Whh = (const float*)d_in[7];
  const float* bih = (const float*)d_in[8];
  const float* bhh = (const float*)d_in[9];
  const float* Ws1 = (const float*)d_in[10];
  const float* bs1 = (const float*)d_in[11];
  const float* Ws2 = (const float*)d_in[12];
  const float* bs2 = (const float*)d_in[13];
  const float* Wp1 = (const float*)d_in[14];
  const float* bp1 = (const float*)d_in[15];
  const float* Wp2 = (const float*)d_in[16];
  const float* bp2 = (const float*)d_in[17];
  const float* Wv1 = (const float*)d_in[18];
  const float* bv1 = (const float*)d_in[19];
  const float* Wv2 = (const float*)d_in[20];
  const float* bv2 = (const float*)d_in[21];
  float* out = (float*)d_out;

  const int Bn = in_sizes[0] / NF;   // 2048
  hipLaunchKernelGGL(seqnet, dim3(Bn), dim3(256), 0, stream,
                     state, acquired, We1, be1, We2, be2, Wih, Whh, bih, bhh,
                     Ws1, bs1, Ws2, bs2, Wp1, bp1, Wp2, bp2, Wv1, bv1, Wv2, bv2,
                     out);
}

// Round 3
// 1058.108 us; speedup vs baseline: 1.0813x; 1.0813x over previous
//
#include <hip/hip_runtime.h>
#include <math.h>

namespace {

constexpr int NF   = 256;   // n_feature / tokens
constexpr int EH   = 128;   // embedder hidden
constexpr int E    = 64;    // embedded dim
constexpr int H    = 64;    // lstm size
constexpr int SHD  = 256;   // shared hidden
constexpr int SD   = 128;   // shared dim
constexpr int NA   = 257;   // n_action
constexpr int NSHUF = 4;

__device__ __forceinline__ float fsig(float x) {   // saturating-safe sigmoid
  return 1.f / (1.f + __expf(-x));
}
__device__ __forceinline__ float ftanh(float x) {  // saturating-safe tanh
  return 1.f - 2.f / (__expf(2.f * x) + 1.f);
}

__global__ __launch_bounds__(256, 4) void seqnet(
    const float* __restrict__ state, const int* __restrict__ acquired,
    const float* __restrict__ We1, const float* __restrict__ be1,
    const float* __restrict__ We2, const float* __restrict__ be2,
    const float* __restrict__ Wih, const float* __restrict__ Whh,
    const float* __restrict__ bih, const float* __restrict__ bhh,
    const float* __restrict__ Ws1, const float* __restrict__ bs1,
    const float* __restrict__ Ws2, const float* __restrict__ bs2,
    const float* __restrict__ Wp1, const float* __restrict__ bp1,
    const float* __restrict__ Wp2, const float* __restrict__ bp2,
    const float* __restrict__ Wv1, const float* __restrict__ bv1,
    const float* __restrict__ Wv2, const float* __restrict__ bv2,
    float* __restrict__ out)
{
  const int b    = blockIdx.x;
  const int t    = threadIdx.x;
  const int lane = t & 63;
  const int wid  = t >> 6;

  // big: phase 1-2 = emb hi-half [256 rows][32 cols], XOR-swizzled (32 KB).
  //      phase 3   = t1(256) | sh(128) | a1(128) | v1(128) overlay.
  __shared__ float big[NF * 32];
  __shared__ int   id_l[NF];
  __shared__ float val_l[NF];
  __shared__ float w_s[NF];
  __shared__ float partial[12][32];   // rows 0-7: hi chunks, 8-11: lo per-wave
  __shared__ int   wcnt[4];
  __shared__ float wmax[4];
  __shared__ float wsum[4];
  __shared__ float qt_s[H];
  __shared__ float ct_s[H];
  __shared__ float att_s[E];
  __shared__ float gates_s[4 * H];
  __shared__ float v_scalar;

  const int sw = t & 31;   // row swizzle key for big

  // ---------------- phase 0: closed-form "argsort" ----------------
  const int ai = (acquired[b * NF + t] != 0) ? 1 : 0;
  const unsigned long long mask = __ballot(ai);
  const int pin = __popcll(mask & ((1ull << lane) - 1ull));
  if (lane == 0) wcnt[wid] = __popcll(mask);
  if (t < H) { qt_s[t] = 0.f; ct_s[t] = 0.f; att_s[t] = 0.f; }
  __syncthreads();
  int pexcl = pin;
  int L = 0;
  #pragma unroll
  for (int w = 0; w < 4; ++w) {
    const int c = wcnt[w];
    if (w < wid) pexcl += c;
    L += c;
  }
  if (ai) {
    const int rank = L - pexcl - 1;      // # acquired with index > t
    id_l[rank]  = t + 1;
    val_l[rank] = state[b * NF + t];
  }
  __syncthreads();

  // ---------------- phase 1: embedder (thread t == token t) ----------------
  float emb[E];   // upper half parked to LDS right after; lo half stays live
  #pragma unroll
  for (int e = 0; e < E; ++e) emb[e] = 0.f;
  if (t < L) {
    const int   id = id_l[t];
    const float v  = val_l[t];
    const float* __restrict__ w1r = We1 + id * EH;
    for (int k = 0; k < EH; k += 4) {
      const float4 wr = *(const float4*)(w1r + k);        // per-lane gather
      const float4 w0 = *(const float4*)(We1 + k);        // uniform
      const float4 bb = *(const float4*)(be1 + k);        // uniform
      const float h0 = fmaxf(fmaf(v, w0.x, wr.x) + bb.x, 0.f);
      const float h1 = fmaxf(fmaf(v, w0.y, wr.y) + bb.y, 0.f);
      const float h2 = fmaxf(fmaf(v, w0.z, wr.z) + bb.z, 0.f);
      const float h3 = fmaxf(fmaf(v, w0.w, wr.w) + bb.w, 0.f);
      const float* __restrict__ w2r = We2 + k * E;        // uniform rows
      #pragma unroll
      for (int e = 0; e < E; e += 4) {
        const float4 r0 = *(const float4*)(w2r + e);
        const float4 r1 = *(const float4*)(w2r + E + e);
        const float4 r2 = *(const float4*)(w2r + 2 * E + e);
        const float4 r3 = *(const float4*)(w2r + 3 * E + e);
        emb[e]   = fmaf(h3, r3.x, fmaf(h2, r2.x, fmaf(h1, r1.x, fmaf(h0, r0.x, emb[e]))));
        emb[e+1] = fmaf(h3, r3.y, fmaf(h2, r2.y, fmaf(h1, r1.y, fmaf(h0, r0.y, emb[e+1]))));
        emb[e+2] = fmaf(h3, r3.z, fmaf(h2, r2.z, fmaf(h1, r1.z, fmaf(h0, r0.z, emb[e+2]))));
        emb[e+3] = fmaf(h3, r3.w, fmaf(h2, r2.w, fmaf(h1, r1.w, fmaf(h0, r0.w, emb[e+3]))));
      }
    }
    #pragma unroll
    for (int e = 0; e < E; ++e) emb[e] += be2[e];
  }
  // park hi half in LDS (zeros for t>=L keep later 0*x sums clean)
  #pragma unroll
  for (int j = 0; j < 32; ++j) big[t * 32 + (j ^ sw)] = emb[32 + j];
  // only emb[0..31] is live from here on

  // ---------------- phase 2: attention + LSTM ----------------
  if (L > 0) {
    const float invL = 1.f / (float)L;
    for (int it = 0; it < NSHUF; ++it) {
      float w;
      if (it == 0) {
        // qt == 0 -> logits 0 (masked) -> uniform softmax over first L tokens
        w = (t < L) ? invL : 0.f;
      } else {
        float a0 = 0.f, a1 = 0.f, a2 = 0.f, a3 = 0.f;
        #pragma unroll
        for (int j = 0; j < 32; j += 4) {
          const float4 q = *(const float4*)(qt_s + j);
          a0 = fmaf(emb[j],     q.x, a0);
          a1 = fmaf(emb[j + 1], q.y, a1);
          a2 = fmaf(emb[j + 2], q.z, a2);
          a3 = fmaf(emb[j + 3], q.w, a3);
        }
        #pragma unroll
        for (int j = 0; j < 32; j += 4) {
          const float4 q = *(const float4*)(qt_s + 32 + j);
          a0 = fmaf(big[t * 32 + ((j)     ^ sw)], q.x, a0);
          a1 = fmaf(big[t * 32 + ((j + 1) ^ sw)], q.y, a1);
          a2 = fmaf(big[t * 32 + ((j + 2) ^ sw)], q.z, a2);
          a3 = fmaf(big[t * 32 + ((j + 3) ^ sw)], q.w, a3);
        }
        const float lg = (t < L) ? (a0 + a1) + (a2 + a3) : -1e30f;
        float m = lg;
        #pragma unroll
        for (int d = 32; d > 0; d >>= 1) m = fmaxf(m, __shfl_xor(m, d));
        if (lane == 0) wmax[wid] = m;
        __syncthreads();
        m = fmaxf(fmaxf(wmax[0], wmax[1]), fmaxf(wmax[2], wmax[3]));
        const float p = (t < L) ? __expf(lg - m) : 0.f;
        float s = p;
        #pragma unroll
        for (int d = 32; d > 0; d >>= 1) s += __shfl_xor(s, d);
        if (lane == 0) wsum[wid] = s;
        __syncthreads();
        s = (wsum[0] + wsum[1]) + (wsum[2] + wsum[3]);
        w = p / s;
      }
      w_s[t] = w;
      __syncthreads();   // w_s + (it==0) big stores visible

      // attended lo (cols 0-31): chunked 16-col register butterfly
      #pragma unroll
      for (int c2 = 0; c2 < 2; ++c2) {
        float u[16];
        #pragma unroll
        for (int j = 0; j < 16; ++j) u[j] = w * emb[c2 * 16 + j];
        #pragma unroll
        for (int j = 0; j < 16; ++j) u[j] += __shfl_xor(u[j], 32);
        #pragma unroll
        for (int j = 0; j < 16; ++j) u[j] += __shfl_xor(u[j], 16);
        #pragma unroll
        for (int step = 0; step < 4; ++step) {
          const int d = 8 >> step;
          const bool hi = (lane & d) != 0;
          #pragma unroll
          for (int i = 0; i < d; ++i) {
            const float keep = hi ? u[i + d] : u[i];
            const float send = hi ? u[i] : u[i + d];
            u[i] = keep + __shfl_xor(send, d);
          }
        }
        if (lane < 16) partial[8 + wid][c2 * 16 + lane] = u[0];
      }

      // attended hi (cols 32-63): (col, token-chunk) cooperative sums from LDS
      {
        const int c = t & 31, chunk = t >> 5;
        const int rbase = chunk * 32;
        float acc0 = 0.f, acc1 = 0.f;
        #pragma unroll
        for (int i = 0; i < 32; i += 2) {
          acc0 = fmaf(w_s[rbase + i],     big[(rbase + i)     * 32 + (c ^ (i))],     acc0);
          acc1 = fmaf(w_s[rbase + i + 1], big[(rbase + i + 1) * 32 + (c ^ (i + 1))], acc1);
        }
        partial[chunk][c] = acc0 + acc1;
      }
      __syncthreads();
      if (t < 32) {
        float s0 = 0.f;
        #pragma unroll
        for (int q = 0; q < 8; ++q) s0 += partial[q][t];
        att_s[32 + t] = s0;
      } else if (t < 64) {
        const int cc = t - 32;
        att_s[cc] = (partial[8][cc] + partial[9][cc]) + (partial[10][cc] + partial[11][cc]);
      }
      __syncthreads();

      // gates[t] = att @ Wih[:,t] (+ qt @ Whh[:,t]) + bih[t] + bhh[t]
      float g0 = 0.f, g1 = 0.f, g2 = 0.f, g3 = 0.f;
      for (int e = 0; e < E; e += 4) {
        const float4 a = *(const float4*)(att_s + e);
        g0 = fmaf(a.x, Wih[(e)     * (4 * H) + t], g0);
        g1 = fmaf(a.y, Wih[(e + 1) * (4 * H) + t], g1);
        g2 = fmaf(a.z, Wih[(e + 2) * (4 * H) + t], g2);
        g3 = fmaf(a.w, Wih[(e + 3) * (4 * H) + t], g3);
      }
      if (it > 0) {
        for (int h = 0; h < H; h += 4) {
          const float4 q = *(const float4*)(qt_s + h);
          g0 = fmaf(q.x, Whh[(h)     * (4 * H) + t], g0);
          g1 = fmaf(q.y, Whh[(h + 1) * (4 * H) + t], g1);
          g2 = fmaf(q.z, Whh[(h + 2) * (4 * H) + t], g2);
          g3 = fmaf(q.w, Whh[(h + 3) * (4 * H) + t], g3);
        }
      }
      gates_s[t] = bih[t] + bhh[t] + (g0 + g1) + (g2 + g3);
      __syncthreads();
      if (t < H) {
        const float ig = gates_s[t];
        const float fg = gates_s[H + t];
        const float gg = gates_s[2 * H + t];
        const float og = gates_s[3 * H + t];
        float c = ct_s[t];
        c = fsig(fg) * c + fsig(ig) * ftanh(gg);
        ct_s[t] = c;
        qt_s[t] = fsig(og) * ftanh(c);
      }
      __syncthreads();
    }
  }

  // ---------------- phase 3: DuelingNet (overlays big) ----------------
  float* t1_s = big;          // 256
  float* sh_s = big + 256;    // 128
  float* a1_s = big + 384;    // 128
  float* v1_s = big + 512;    // 128
  {
    float x0 = 0.f, x1 = 0.f, x2 = 0.f, x3 = 0.f;
    for (int k = 0; k < E; k += 4) {
      const float4 a = *(const float4*)(att_s + k);
      x0 = fmaf(a.x, Ws1[(k)     * SHD + t], x0);
      x1 = fmaf(a.y, Ws1[(k + 1) * SHD + t], x1);
      x2 = fmaf(a.z, Ws1[(k + 2) * SHD + t], x2);
      x3 = fmaf(a.w, Ws1[(k + 3) * SHD + t], x3);
    }
    for (int k = 0; k < H; k += 4) {
      const float4 q = *(const float4*)(qt_s + k);
      x0 = fmaf(q.x, Ws1[(E + k)     * SHD + t], x0);
      x1 = fmaf(q.y, Ws1[(E + k + 1) * SHD + t], x1);
      x2 = fmaf(q.z, Ws1[(E + k + 2) * SHD + t], x2);
      x3 = fmaf(q.w, Ws1[(E + k + 3) * SHD + t], x3);
    }
    const float r = fmaxf(bs1[t] + (x0 + x1) + (x2 + x3), 0.f);
    __syncthreads();           // ensure all big (emb-hi) reads are done
    t1_s[t] = r;
  }
  __syncthreads();
  if (t < SD) {
    float x0 = 0.f, x1 = 0.f, x2 = 0.f, x3 = 0.f;
    for (int k = 0; k < SHD; k += 4) {
      const float4 a = *(const float4*)(t1_s + k);
      x0 = fmaf(a.x, Ws2[(k)     * SD + t], x0);
      x1 = fmaf(a.y, Ws2[(k + 1) * SD + t], x1);
      x2 = fmaf(a.z, Ws2[(k + 2) * SD + t], x2);
      x3 = fmaf(a.w, Ws2[(k + 3) * SD + t], x3);
    }
    sh_s[t] = fmaxf(bs2[t] + (x0 + x1) + (x2 + x3), 0.f);
  }
  __syncthreads();
  if (t < SD) {
    float x0 = 0.f, x1 = 0.f, x2 = 0.f, x3 = 0.f;
    for (int k = 0; k < SD; k += 4) {
      const float4 a = *(const float4*)(sh_s + k);
      x0 = fmaf(a.x, Wp1[(k)     * SD + t], x0);
      x1 = fmaf(a.y, Wp1[(k + 1) * SD + t], x1);
      x2 = fmaf(a.z, Wp1[(k + 2) * SD + t], x2);
      x3 = fmaf(a.w, Wp1[(k + 3) * SD + t], x3);
    }
    a1_s[t] = fmaxf(bp1[t] + (x0 + x1) + (x2 + x3), 0.f);
  } else {
    const int tt = t - SD;
    float x0 = 0.f, x1 = 0.f, x2 = 0.f, x3 = 0.f;
    for (int k = 0; k < SD; k += 4) {
      const float4 a = *(const float4*)(sh_s + k);
      x0 = fmaf(a.x, Wv1[(k)     * SD + tt], x0);
      x1 = fmaf(a.y, Wv1[(k + 1) * SD + tt], x1);
      x2 = fmaf(a.z, Wv1[(k + 2) * SD + tt], x2);
      x3 = fmaf(a.w, Wv1[(k + 3) * SD + tt], x3);
    }
    v1_s[tt] = fmaxf(bv1[tt] + (x0 + x1) + (x2 + x3), 0.f);
  }
  __syncthreads();
  if (wid == 1) {   // v = v1 @ Wv2 + bv2 (wave 1; wave 0 has the adv2 extra column)
    float vv = fmaf(v1_s[lane], Wv2[lane], v1_s[lane + 64] * Wv2[lane + 64]);
    #pragma unroll
    for (int d = 32; d > 0; d >>= 1) vv += __shfl_xor(vv, d);
    if (lane == 0) v_scalar = vv + bv2[0];
  }
  // adv: one column per thread (+ col 256 on thread 0)
  float x0 = 0.f, x1 = 0.f, x2 = 0.f, x3 = 0.f;
  for (int k = 0; k < SD; k += 4) {
    const float4 a = *(const float4*)(a1_s + k);
    x0 = fmaf(a.x, Wp2[(k)     * NA + t], x0);
    x1 = fmaf(a.y, Wp2[(k + 1) * NA + t], x1);
    x2 = fmaf(a.z, Wp2[(k + 2) * NA + t], x2);
    x3 = fmaf(a.w, Wp2[(k + 3) * NA + t], x3);
  }
  const float adv = bp2[t] + (x0 + x1) + (x2 + x3);
  float adv2 = 0.f;
  if (t == 0) {
    float y0 = 0.f, y1 = 0.f, y2 = 0.f, y3 = 0.f;
    for (int k = 0; k < SD; k += 4) {
      const float4 a = *(const float4*)(a1_s + k);
      y0 = fmaf(a.x, Wp2[(k)     * NA + (NA - 1)], y0);
      y1 = fmaf(a.y, Wp2[(k + 1) * NA + (NA - 1)], y1);
      y2 = fmaf(a.z, Wp2[(k + 2) * NA + (NA - 1)], y2);
      y3 = fmaf(a.w, Wp2[(k + 3) * NA + (NA - 1)], y3);
    }
    adv2 = bp2[NA - 1] + (y0 + y1) + (y2 + y3);
  }
  float ssum = adv + adv2;
  #pragma unroll
  for (int d = 32; d > 0; d >>= 1) ssum += __shfl_xor(ssum, d);
  if (lane == 0) wsum[wid] = ssum;
  __syncthreads();
  const float mean = ((wsum[0] + wsum[1]) + (wsum[2] + wsum[3])) * (1.f / (float)NA);
  const float vv = v_scalar;
  out[b * NA + t] = vv + adv - mean;
  if (t == 0) out[b * NA + (NA - 1)] = vv + adv2 - mean;
}

}  // namespace

extern "C" void kernel_launch(void* const* d_in, const int* in_sizes, int n_in,
                              void* d_out, int out_size, void* d_ws, size_t ws_size,
                              hipStream_t stream) {
  const float* state    = (const float*)d_in[0];
  const int*   acquired = (const int*)d_in[1];
  const float* We1 = (const float*)d_in[2];
  const float* be1 = (const float*)d_in[3];
  const float* We2 = (const float*)d_in[4];
  const float* be2 = (const float*)d_in[5];
  const float* Wih = (const float*)d_in[6];
  const float* Whh = (const float*)d_in[7];
  const float* bih = (const float*)d_in[8];
  const float* bhh = (const float*)d_in[9];
  const float* Ws1 = (const float*)d_in[10];
  const float* bs1 = (const float*)d_in[11];
  const float* Ws2 = (const float*)d_in[12];
  const float* bs2 = (const float*)d_in[13];
  const float* Wp1 = (const float*)d_in[14];
  const float* bp1 = (const float*)d_in[15];
  const float* Wp2 = (const float*)d_in[16];
  const float* bp2 = (const float*)d_in[17];
  const float* Wv1 = (const float*)d_in[18];
  const float* bv1 = (const float*)d_in[19];
  const float* Wv2 = (const float*)d_in[20];
  const float* bv2 = (const float*)d_in[21];
  float* out = (float*)d_out;

  const int Bn = in_sizes[0] / NF;   // 2048
  hipLaunchKernelGGL(seqnet, dim3(Bn), dim3(256), 0, stream,
                     state, acquired, We1, be1, We2, be2, Wih, Whh, bih, bhh,
                     Ws1, bs1, Ws2, bs2, Wp1, bp1, Wp2, bp2, Wv1, bv1, Wv2, bv2,
                     out);
}

// Round 4
// 660.300 us; speedup vs baseline: 1.7327x; 1.6025x over previous
//
#include <hip/hip_runtime.h>
#include <math.h>

namespace {

constexpr int NF   = 256;   // n_feature / tokens
constexpr int EH   = 128;   // embedder hidden
constexpr int E    = 64;    // embedded dim
constexpr int H    = 64;    // lstm size
constexpr int SHD  = 256;   // shared hidden
constexpr int SD   = 128;   // shared dim
constexpr int NA   = 257;   // n_action
constexpr int NSHUF = 4;

__device__ __forceinline__ float fsig(float x) {   // saturating-safe sigmoid
  return 1.f / (1.f + __expf(-x));
}
__device__ __forceinline__ float ftanh(float x) {  // saturating-safe tanh
  return 1.f - 2.f / (__expf(2.f * x) + 1.f);
}

// NOTE: no min-waves arg. (256,4) empirically forces a 64-VGPR budget on
// gfx950 and spills ~2.3 GB to scratch (rounds 2-3). Let the allocator
// size to the live set; the two-pass embedder keeps peak live < 128.
__global__ __launch_bounds__(256) void seqnet(
    const float* __restrict__ state, const int* __restrict__ acquired,
    const float* __restrict__ We1, const float* __restrict__ be1,
    const float* __restrict__ We2, const float* __restrict__ be2,
    const float* __restrict__ Wih, const float* __restrict__ Whh,
    const float* __restrict__ bih, const float* __restrict__ bhh,
    const float* __restrict__ Ws1, const float* __restrict__ bs1,
    const float* __restrict__ Ws2, const float* __restrict__ bs2,
    const float* __restrict__ Wp1, const float* __restrict__ bp1,
    const float* __restrict__ Wp2, const float* __restrict__ bp2,
    const float* __restrict__ Wv1, const float* __restrict__ bv1,
    const float* __restrict__ Wv2, const float* __restrict__ bv2,
    float* __restrict__ out)
{
  const int b    = blockIdx.x;
  const int t    = threadIdx.x;
  const int lane = t & 63;
  const int wid  = t >> 6;

  // big: phase 1-2 = emb hi-half [256 rows][32 cols], XOR-swizzled (32 KB).
  //      phase 3   = t1(256) | sh(128) | a1(128) | v1(128) overlay.
  __shared__ float big[NF * 32];
  __shared__ int   id_l[NF];
  __shared__ float val_l[NF];
  __shared__ float w_s[NF];
  __shared__ float partial[12][32];   // rows 0-7: hi chunks, 8-11: lo per-wave
  __shared__ int   wcnt[4];
  __shared__ float wmax[4];
  __shared__ float wsum[4];
  __shared__ float qt_s[H];
  __shared__ float ct_s[H];
  __shared__ float att_s[E];
  __shared__ float gates_s[4 * H];
  __shared__ float v_scalar;

  const int sw = t & 31;   // row swizzle key for big

  // ---------------- phase 0: closed-form "argsort" ----------------
  const int ai = (acquired[b * NF + t] != 0) ? 1 : 0;
  const unsigned long long mask = __ballot(ai);
  const int pin = __popcll(mask & ((1ull << lane) - 1ull));
  if (lane == 0) wcnt[wid] = __popcll(mask);
  if (t < H) { qt_s[t] = 0.f; ct_s[t] = 0.f; att_s[t] = 0.f; }
  __syncthreads();
  int pexcl = pin;
  int L = 0;
  #pragma unroll
  for (int w = 0; w < 4; ++w) {
    const int c = wcnt[w];
    if (w < wid) pexcl += c;
    L += c;
  }
  if (ai) {
    const int rank = L - pexcl - 1;      // # acquired with index > t
    id_l[rank]  = t + 1;
    val_l[rank] = state[b * NF + t];
  }
  __syncthreads();

  // ---------------- phase 1: embedder, two passes (32 accums each) ----------
  const int   id = (t < L) ? id_l[t] : 0;
  const float v  = (t < L) ? val_l[t] : 0.f;
  const float* __restrict__ w1r = We1 + id * EH;

  // pass A: hi columns 32..63 -> park directly into swizzled LDS
  {
    float eh[32];
    #pragma unroll
    for (int j = 0; j < 32; ++j) eh[j] = 0.f;
    if (t < L) {
      for (int k = 0; k < EH; k += 4) {
        const float4 wr = *(const float4*)(w1r + k);        // per-lane gather
        const float4 w0 = *(const float4*)(We1 + k);        // uniform
        const float4 bb = *(const float4*)(be1 + k);        // uniform
        const float h0 = fmaxf(fmaf(v, w0.x, wr.x) + bb.x, 0.f);
        const float h1 = fmaxf(fmaf(v, w0.y, wr.y) + bb.y, 0.f);
        const float h2 = fmaxf(fmaf(v, w0.z, wr.z) + bb.z, 0.f);
        const float h3 = fmaxf(fmaf(v, w0.w, wr.w) + bb.w, 0.f);
        const float* __restrict__ w2r = We2 + k * E + 32;   // hi cols, uniform
        #pragma unroll
        for (int j = 0; j < 32; j += 4) {
          const float4 r0 = *(const float4*)(w2r + j);
          const float4 r1 = *(const float4*)(w2r + E + j);
          const float4 r2 = *(const float4*)(w2r + 2 * E + j);
          const float4 r3 = *(const float4*)(w2r + 3 * E + j);
          eh[j]   = fmaf(h3, r3.x, fmaf(h2, r2.x, fmaf(h1, r1.x, fmaf(h0, r0.x, eh[j]))));
          eh[j+1] = fmaf(h3, r3.y, fmaf(h2, r2.y, fmaf(h1, r1.y, fmaf(h0, r0.y, eh[j+1]))));
          eh[j+2] = fmaf(h3, r3.z, fmaf(h2, r2.z, fmaf(h1, r1.z, fmaf(h0, r0.z, eh[j+2]))));
          eh[j+3] = fmaf(h3, r3.w, fmaf(h2, r2.w, fmaf(h1, r1.w, fmaf(h0, r0.w, eh[j+3]))));
        }
      }
      #pragma unroll
      for (int j = 0; j < 32; ++j) eh[j] += be2[32 + j];
    }
    #pragma unroll
    for (int j = 0; j < 32; ++j) big[t * 32 + (j ^ sw)] = eh[j];
  }

  // pass B: lo columns 0..31 -> stay in registers through phase 2
  float emb[32];
  #pragma unroll
  for (int j = 0; j < 32; ++j) emb[j] = 0.f;
  if (t < L) {
    for (int k = 0; k < EH; k += 4) {
      const float4 wr = *(const float4*)(w1r + k);
      const float4 w0 = *(const float4*)(We1 + k);
      const float4 bb = *(const float4*)(be1 + k);
      const float h0 = fmaxf(fmaf(v, w0.x, wr.x) + bb.x, 0.f);
      const float h1 = fmaxf(fmaf(v, w0.y, wr.y) + bb.y, 0.f);
      const float h2 = fmaxf(fmaf(v, w0.z, wr.z) + bb.z, 0.f);
      const float h3 = fmaxf(fmaf(v, w0.w, wr.w) + bb.w, 0.f);
      const float* __restrict__ w2r = We2 + k * E;          // lo cols, uniform
      #pragma unroll
      for (int j = 0; j < 32; j += 4) {
        const float4 r0 = *(const float4*)(w2r + j);
        const float4 r1 = *(const float4*)(w2r + E + j);
        const float4 r2 = *(const float4*)(w2r + 2 * E + j);
        const float4 r3 = *(const float4*)(w2r + 3 * E + j);
        emb[j]   = fmaf(h3, r3.x, fmaf(h2, r2.x, fmaf(h1, r1.x, fmaf(h0, r0.x, emb[j]))));
        emb[j+1] = fmaf(h3, r3.y, fmaf(h2, r2.y, fmaf(h1, r1.y, fmaf(h0, r0.y, emb[j+1]))));
        emb[j+2] = fmaf(h3, r3.z, fmaf(h2, r2.z, fmaf(h1, r1.z, fmaf(h0, r0.z, emb[j+2]))));
        emb[j+3] = fmaf(h3, r3.w, fmaf(h2, r2.w, fmaf(h1, r1.w, fmaf(h0, r0.w, emb[j+3]))));
      }
    }
    #pragma unroll
    for (int j = 0; j < 32; ++j) emb[j] += be2[j];
  }

  // ---------------- phase 2: attention + LSTM ----------------
  if (L > 0) {
    const float invL = 1.f / (float)L;
    for (int it = 0; it < NSHUF; ++it) {
      float w;
      if (it == 0) {
        // qt == 0 -> logits 0 (masked) -> uniform softmax over first L tokens
        w = (t < L) ? invL : 0.f;
      } else {
        float a0 = 0.f, a1 = 0.f, a2 = 0.f, a3 = 0.f;
        #pragma unroll
        for (int j = 0; j < 32; j += 4) {
          const float4 q = *(const float4*)(qt_s + j);
          a0 = fmaf(emb[j],     q.x, a0);
          a1 = fmaf(emb[j + 1], q.y, a1);
          a2 = fmaf(emb[j + 2], q.z, a2);
          a3 = fmaf(emb[j + 3], q.w, a3);
        }
        #pragma unroll
        for (int j = 0; j < 32; j += 4) {
          const float4 q = *(const float4*)(qt_s + 32 + j);
          a0 = fmaf(big[t * 32 + ((j)     ^ sw)], q.x, a0);
          a1 = fmaf(big[t * 32 + ((j + 1) ^ sw)], q.y, a1);
          a2 = fmaf(big[t * 32 + ((j + 2) ^ sw)], q.z, a2);
          a3 = fmaf(big[t * 32 + ((j + 3) ^ sw)], q.w, a3);
        }
        const float lg = (t < L) ? (a0 + a1) + (a2 + a3) : -1e30f;
        float m = lg;
        #pragma unroll
        for (int d = 32; d > 0; d >>= 1) m = fmaxf(m, __shfl_xor(m, d));
        if (lane == 0) wmax[wid] = m;
        __syncthreads();
        m = fmaxf(fmaxf(wmax[0], wmax[1]), fmaxf(wmax[2], wmax[3]));
        const float p = (t < L) ? __expf(lg - m) : 0.f;
        float s = p;
        #pragma unroll
        for (int d = 32; d > 0; d >>= 1) s += __shfl_xor(s, d);
        if (lane == 0) wsum[wid] = s;
        __syncthreads();
        s = (wsum[0] + wsum[1]) + (wsum[2] + wsum[3]);
        w = p / s;
      }
      w_s[t] = w;
      __syncthreads();   // w_s + parked big stores visible

      // attended lo (cols 0-31): chunked 16-col register butterfly
      #pragma unroll
      for (int c2 = 0; c2 < 2; ++c2) {
        float u[16];
        #pragma unroll
        for (int j = 0; j < 16; ++j) u[j] = w * emb[c2 * 16 + j];
        #pragma unroll
        for (int j = 0; j < 16; ++j) u[j] += __shfl_xor(u[j], 32);
        #pragma unroll
        for (int j = 0; j < 16; ++j) u[j] += __shfl_xor(u[j], 16);
        #pragma unroll
        for (int step = 0; step < 4; ++step) {
          const int d = 8 >> step;
          const bool hi = (lane & d) != 0;
          #pragma unroll
          for (int i = 0; i < d; ++i) {
            const float keep = hi ? u[i + d] : u[i];
            const float send = hi ? u[i] : u[i + d];
            u[i] = keep + __shfl_xor(send, d);
          }
        }
        if (lane < 16) partial[8 + wid][c2 * 16 + lane] = u[0];
      }

      // attended hi (cols 32-63): (col, token-chunk) cooperative sums from LDS
      {
        const int c = t & 31, chunk = t >> 5;
        const int rbase = chunk * 32;
        float acc0 = 0.f, acc1 = 0.f;
        #pragma unroll
        for (int i = 0; i < 32; i += 2) {
          acc0 = fmaf(w_s[rbase + i],     big[(rbase + i)     * 32 + (c ^ (i))],     acc0);
          acc1 = fmaf(w_s[rbase + i + 1], big[(rbase + i + 1) * 32 + (c ^ (i + 1))], acc1);
        }
        partial[chunk][c] = acc0 + acc1;
      }
      __syncthreads();
      if (t < 32) {
        float s0 = 0.f;
        #pragma unroll
        for (int q = 0; q < 8; ++q) s0 += partial[q][t];
        att_s[32 + t] = s0;
      } else if (t < 64) {
        const int cc = t - 32;
        att_s[cc] = (partial[8][cc] + partial[9][cc]) + (partial[10][cc] + partial[11][cc]);
      }
      __syncthreads();

      // gates[t] = att @ Wih[:,t] (+ qt @ Whh[:,t]) + bih[t] + bhh[t]
      float g0 = 0.f, g1 = 0.f, g2 = 0.f, g3 = 0.f;
      for (int e = 0; e < E; e += 4) {
        const float4 a = *(const float4*)(att_s + e);
        g0 = fmaf(a.x, Wih[(e)     * (4 * H) + t], g0);
        g1 = fmaf(a.y, Wih[(e + 1) * (4 * H) + t], g1);
        g2 = fmaf(a.z, Wih[(e + 2) * (4 * H) + t], g2);
        g3 = fmaf(a.w, Wih[(e + 3) * (4 * H) + t], g3);
      }
      if (it > 0) {
        for (int h = 0; h < H; h += 4) {
          const float4 q = *(const float4*)(qt_s + h);
          g0 = fmaf(q.x, Whh[(h)     * (4 * H) + t], g0);
          g1 = fmaf(q.y, Whh[(h + 1) * (4 * H) + t], g1);
          g2 = fmaf(q.z, Whh[(h + 2) * (4 * H) + t], g2);
          g3 = fmaf(q.w, Whh[(h + 3) * (4 * H) + t], g3);
        }
      }
      gates_s[t] = bih[t] + bhh[t] + (g0 + g1) + (g2 + g3);
      __syncthreads();
      if (t < H) {
        const float ig = gates_s[t];
        const float fg = gates_s[H + t];
        const float gg = gates_s[2 * H + t];
        const float og = gates_s[3 * H + t];
        float c = ct_s[t];
        c = fsig(fg) * c + fsig(ig) * ftanh(gg);
        ct_s[t] = c;
        qt_s[t] = fsig(og) * ftanh(c);
      }
      __syncthreads();
    }
  }

  // ---------------- phase 3: DuelingNet (overlays big) ----------------
  float* t1_s = big;          // 256
  float* sh_s = big + 256;    // 128
  float* a1_s = big + 384;    // 128
  float* v1_s = big + 512;    // 128
  {
    float x0 = 0.f, x1 = 0.f, x2 = 0.f, x3 = 0.f;
    for (int k = 0; k < E; k += 4) {
      const float4 a = *(const float4*)(att_s + k);
      x0 = fmaf(a.x, Ws1[(k)     * SHD + t], x0);
      x1 = fmaf(a.y, Ws1[(k + 1) * SHD + t], x1);
      x2 = fmaf(a.z, Ws1[(k + 2) * SHD + t], x2);
      x3 = fmaf(a.w, Ws1[(k + 3) * SHD + t], x3);
    }
    for (int k = 0; k < H; k += 4) {
      const float4 q = *(const float4*)(qt_s + k);
      x0 = fmaf(q.x, Ws1[(E + k)     * SHD + t], x0);
      x1 = fmaf(q.y, Ws1[(E + k + 1) * SHD + t], x1);
      x2 = fmaf(q.z, Ws1[(E + k + 2) * SHD + t], x2);
      x3 = fmaf(q.w, Ws1[(E + k + 3) * SHD + t], x3);
    }
    const float r = fmaxf(bs1[t] + (x0 + x1) + (x2 + x3), 0.f);
    __syncthreads();           // ensure all big (emb-hi) reads are done
    t1_s[t] = r;
  }
  __syncthreads();
  if (t < SD) {
    float x0 = 0.f, x1 = 0.f, x2 = 0.f, x3 = 0.f;
    for (int k = 0; k < SHD; k += 4) {
      const float4 a = *(const float4*)(t1_s + k);
      x0 = fmaf(a.x, Ws2[(k)     * SD + t], x0);
      x1 = fmaf(a.y, Ws2[(k + 1) * SD + t], x1);
      x2 = fmaf(a.z, Ws2[(k + 2) * SD + t], x2);
      x3 = fmaf(a.w, Ws2[(k + 3) * SD + t], x3);
    }
    sh_s[t] = fmaxf(bs2[t] + (x0 + x1) + (x2 + x3), 0.f);
  }
  __syncthreads();
  if (t < SD) {
    float x0 = 0.f, x1 = 0.f, x2 = 0.f, x3 = 0.f;
    for (int k = 0; k < SD; k += 4) {
      const float4 a = *(const float4*)(sh_s + k);
      x0 = fmaf(a.x, Wp1[(k)     * SD + t], x0);
      x1 = fmaf(a.y, Wp1[(k + 1) * SD + t], x1);
      x2 = fmaf(a.z, Wp1[(k + 2) * SD + t], x2);
      x3 = fmaf(a.w, Wp1[(k + 3) * SD + t], x3);
    }
    a1_s[t] = fmaxf(bp1[t] + (x0 + x1) + (x2 + x3), 0.f);
  } else {
    const int tt = t - SD;
    float x0 = 0.f, x1 = 0.f, x2 = 0.f, x3 = 0.f;
    for (int k = 0; k < SD; k += 4) {
      const float4 a = *(const float4*)(sh_s + k);
      x0 = fmaf(a.x, Wv1[(k)     * SD + tt], x0);
      x1 = fmaf(a.y, Wv1[(k + 1) * SD + tt], x1);
      x2 = fmaf(a.z, Wv1[(k + 2) * SD + tt], x2);
      x3 = fmaf(a.w, Wv1[(k + 3) * SD + tt], x3);
    }
    v1_s[tt] = fmaxf(bv1[tt] + (x0 + x1) + (x2 + x3), 0.f);
  }
  __syncthreads();
  if (wid == 1) {   // v = v1 @ Wv2 + bv2 (wave 1; wave 0 has the adv2 extra column)
    float vv = fmaf(v1_s[lane], Wv2[lane], v1_s[lane + 64] * Wv2[lane + 64]);
    #pragma unroll
    for (int d = 32; d > 0; d >>= 1) vv += __shfl_xor(vv, d);
    if (lane == 0) v_scalar = vv + bv2[0];
  }
  // adv: one column per thread (+ col 256 on thread 0)
  float x0 = 0.f, x1 = 0.f, x2 = 0.f, x3 = 0.f;
  for (int k = 0; k < SD; k += 4) {
    const float4 a = *(const float4*)(a1_s + k);
    x0 = fmaf(a.x, Wp2[(k)     * NA + t], x0);
    x1 = fmaf(a.y, Wp2[(k + 1) * NA + t], x1);
    x2 = fmaf(a.z, Wp2[(k + 2) * NA + t], x2);
    x3 = fmaf(a.w, Wp2[(k + 3) * NA + t], x3);
  }
  const float adv = bp2[t] + (x0 + x1) + (x2 + x3);
  float adv2 = 0.f;
  if (t == 0) {
    float y0 = 0.f, y1 = 0.f, y2 = 0.f, y3 = 0.f;
    for (int k = 0; k < SD; k += 4) {
      const float4 a = *(const float4*)(a1_s + k);
      y0 = fmaf(a.x, Wp2[(k)     * NA + (NA - 1)], y0);
      y1 = fmaf(a.y, Wp2[(k + 1) * NA + (NA - 1)], y1);
      y2 = fmaf(a.z, Wp2[(k + 2) * NA + (NA - 1)], y2);
      y3 = fmaf(a.w, Wp2[(k + 3) * NA + (NA - 1)], y3);
    }
    adv2 = bp2[NA - 1] + (y0 + y1) + (y2 + y3);
  }
  float ssum = adv + adv2;
  #pragma unroll
  for (int d = 32; d > 0; d >>= 1) ssum += __shfl_xor(ssum, d);
  if (lane == 0) wsum[wid] = ssum;
  __syncthreads();
  const float mean = ((wsum[0] + wsum[1]) + (wsum[2] + wsum[3])) * (1.f / (float)NA);
  const float vv = v_scalar;
  out[b * NA + t] = vv + adv - mean;
  if (t == 0) out[b * NA + (NA - 1)] = vv + adv2 - mean;
}

}  // namespace

extern "C" void kernel_launch(void* const* d_in, const int* in_sizes, int n_in,
                              void* d_out, int out_size, void* d_ws, size_t ws_size,
                              hipStream_t stream) {
  const float* state    = (const float*)d_in[0];
  const int*   acquired = (const int*)d_in[1];
  const float* We1 = (const float*)d_in[2];
  const float* be1 = (const float*)d_in[3];
  const float* We2 = (const float*)d_in[4];
  const float* be2 = (const float*)d_in[5];
  const float* Wih = (const float*)d_in[6];
  const float* Whh = (const float*)d_in[7];
  const float* bih = (const float*)d_in[8];
  const float* bhh = (const float*)d_in[9];
  const float* Ws1 = (const float*)d_in[10];
  const float* bs1 = (const float*)d_in[11];
  const float* Ws2 = (const float*)d_in[12];
  const float* bs2 = (const float*)d_in[13];
  const float* Wp1 = (const float*)d_in[14];
  const float* bp1 = (const float*)d_in[15];
  const float* Wp2 = (const float*)d_in[16];
  const float* bp2 = (const float*)d_in[17];
  const float* Wv1 = (const float*)d_in[18];
  const float* bv1 = (const float*)d_in[19];
  const float* Wv2 = (const float*)d_in[20];
  const float* bv2 = (const float*)d_in[21];
  float* out = (float*)d_out;

  const int Bn = in_sizes[0] / NF;   // 2048
  hipLaunchKernelGGL(seqnet, dim3(Bn), dim3(256), 0, stream,
                     state, acquired, We1, be1, We2, be2, Wih, Whh, bih, bhh,
                     Ws1, bs1, Ws2, bs2, Wp1, bp1, Wp2, bp2, Wv1, bv1, Wv2, bv2,
                     out);
}

// Round 5
// 584.905 us; speedup vs baseline: 1.9561x; 1.1289x over previous
//
#include <hip/hip_runtime.h>
#include <math.h>

namespace {

constexpr int NF   = 256;   // n_feature / tokens
constexpr int EH   = 128;   // embedder hidden
constexpr int E    = 64;    // embedded dim
constexpr int EP   = E + 1; // padded LDS row stride (odd => conflict-free both axes)
constexpr int H    = 64;    // lstm size
constexpr int SHD  = 256;   // shared hidden
constexpr int SD   = 128;   // shared dim
constexpr int NA   = 257;   // n_action
constexpr int NSHUF = 4;

__device__ __forceinline__ float fsig(float x) {   // saturating-safe sigmoid
  return 1.f / (1.f + __expf(-x));
}
__device__ __forceinline__ float ftanh(float x) {  // saturating-safe tanh
  return 1.f - 2.f / (__expf(2.f * x) + 1.f);
}

// waves_per_eu(4,4): pin the <=128-VGPR tier exactly. Lessons: launch_bounds
// min-waves => allocator greedily shrinks to 64 VGPR and spills GBs (r2/r3);
// no bound => balloons to 256 VGPR and halves occupancy (r4).
__global__ __launch_bounds__(512)
__attribute__((amdgpu_waves_per_eu(4, 4)))
void seqnet(
    const float* __restrict__ state, const int* __restrict__ acquired,
    const float* __restrict__ We1, const float* __restrict__ be1,
    const float* __restrict__ We2, const float* __restrict__ be2,
    const float* __restrict__ Wih, const float* __restrict__ Whh,
    const float* __restrict__ bih, const float* __restrict__ bhh,
    const float* __restrict__ Ws1, const float* __restrict__ bs1,
    const float* __restrict__ Ws2, const float* __restrict__ bs2,
    const float* __restrict__ Wp1, const float* __restrict__ bp1,
    const float* __restrict__ Wp2, const float* __restrict__ bp2,
    const float* __restrict__ Wv1, const float* __restrict__ bv1,
    const float* __restrict__ Wv2, const float* __restrict__ bv2,
    float* __restrict__ out)
{
  const int b    = blockIdx.x;
  const int t    = threadIdx.x;   // 0..511
  const int lane = t & 63;
  const int wid  = t >> 6;        // 0..7

  __shared__ float emb_s[NF * EP];                       // 66,560 B, fp32 emb
  __shared__ int   id_l[NF];
  __shared__ float val_l[NF];
  __shared__ float w_s[NF];
  __shared__ __align__(16) float red_s[512];             // generic reduction buf
  __shared__ __align__(16) float t1_s[SHD];
  __shared__ __align__(16) float sh_s[SD];
  __shared__ __align__(16) float a1_s[SD];
  __shared__ __align__(16) float v1_s[SD];
  __shared__ int   wcnt[4];
  __shared__ float wred[8];
  __shared__ __align__(16) float qt_s[H];
  __shared__ float ct_s[H];
  __shared__ __align__(16) float att_s[E];
  __shared__ float v_scalar;

  // ---------------- phase 0: closed-form "argsort" ----------------
  // descending stable sort of acquired*(i+1) == acquired indices, largest first
  int ai = 0, pin = 0;
  if (t < NF) {
    ai = (acquired[b * NF + t] != 0) ? 1 : 0;
    const unsigned long long mask = __ballot(ai);
    pin = __popcll(mask & ((1ull << lane) - 1ull));
    if (lane == 0) wcnt[wid] = __popcll(mask);    // wid 0..3 here
  }
  if (t < H) { qt_s[t] = 0.f; ct_s[t] = 0.f; att_s[t] = 0.f; }
  __syncthreads();
  const int L = wcnt[0] + wcnt[1] + wcnt[2] + wcnt[3];
  if (t < NF && ai) {
    int pexcl = pin;
    #pragma unroll
    for (int w = 0; w < 4; ++w) if (w < wid) pexcl += wcnt[w];
    const int rank = L - pexcl - 1;               // # acquired with index > t
    id_l[rank]  = t + 1;
    val_l[rank] = state[b * NF + t];
  }
  __syncthreads();

  // ---------------- phase 1: embedder ----------------
  // wave -> 16-col chunk (cb), lane -> token; 2 passes over token halves.
  // hid_k = relu(v*We1[0,k] + We1[id,k] + be1[k]); emb = hid @ We2 + be2
  {
    const int cb = (wid & 3) * 16;          // column base of this wave
    const int tb = (wid >> 2) * 64;         // token sub-base (0 or 64)
    for (int p = 0; p < 2; ++p) {
      const int tok = tb + p * 128 + lane;
      float acc[16];
      #pragma unroll
      for (int j = 0; j < 16; ++j) acc[j] = 0.f;
      if (tok < L) {
        const int   id = id_l[tok];
        const float v  = val_l[tok];
        const float* __restrict__ w1r = We1 + id * EH;
        for (int k = 0; k < EH; k += 4) {
          const float4 wr = *(const float4*)(w1r + k);     // per-lane gather
          const float4 w0 = *(const float4*)(We1 + k);     // uniform
          const float4 bb = *(const float4*)(be1 + k);     // uniform
          const float h0 = fmaxf(fmaf(v, w0.x, wr.x) + bb.x, 0.f);
          const float h1 = fmaxf(fmaf(v, w0.y, wr.y) + bb.y, 0.f);
          const float h2 = fmaxf(fmaf(v, w0.z, wr.z) + bb.z, 0.f);
          const float h3 = fmaxf(fmaf(v, w0.w, wr.w) + bb.w, 0.f);
          const float* __restrict__ w2 = We2 + k * E + cb; // uniform rows
          #pragma unroll
          for (int j = 0; j < 16; j += 4) {
            const float4 r0 = *(const float4*)(w2 + j);
            const float4 r1 = *(const float4*)(w2 + E + j);
            const float4 r2 = *(const float4*)(w2 + 2 * E + j);
            const float4 r3 = *(const float4*)(w2 + 3 * E + j);
            acc[j]   = fmaf(h3, r3.x, fmaf(h2, r2.x, fmaf(h1, r1.x, fmaf(h0, r0.x, acc[j]))));
            acc[j+1] = fmaf(h3, r3.y, fmaf(h2, r2.y, fmaf(h1, r1.y, fmaf(h0, r0.y, acc[j+1]))));
            acc[j+2] = fmaf(h3, r3.z, fmaf(h2, r2.z, fmaf(h1, r1.z, fmaf(h0, r0.z, acc[j+2]))));
            acc[j+3] = fmaf(h3, r3.w, fmaf(h2, r2.w, fmaf(h1, r1.w, fmaf(h0, r0.w, acc[j+3]))));
          }
        }
        #pragma unroll
        for (int j = 0; j < 16; ++j) acc[j] += be2[cb + j];
      }
      // tok >= L rows stay 0 (multiplied by w=0 later; avoids NaN garbage)
      #pragma unroll
      for (int j = 0; j < 16; ++j) emb_s[tok * EP + cb + j] = acc[j];
    }
  }
  __syncthreads();

  // ---------------- phase 2: attention + LSTM ----------------
  if (L > 0) {
    const float invL = 1.f / (float)L;
    for (int it = 0; it < NSHUF; ++it) {
      float w = 0.f;
      if (it == 0) {
        // qt == 0 -> masked logits all 0 -> uniform softmax over first L
        if (t < NF) w = (t < L) ? invL : 0.f;
      } else {
        float lg = -1e30f;
        if (t < NF) {
          float a0 = 0.f, a1 = 0.f, a2 = 0.f, a3 = 0.f;
          const float* __restrict__ er = emb_s + t * EP;
          #pragma unroll
          for (int j = 0; j < E; j += 4) {
            const float4 q = *(const float4*)(qt_s + j);
            a0 = fmaf(er[j],     q.x, a0);
            a1 = fmaf(er[j + 1], q.y, a1);
            a2 = fmaf(er[j + 2], q.z, a2);
            a3 = fmaf(er[j + 3], q.w, a3);
          }
          if (t < L) lg = (a0 + a1) + (a2 + a3);
        }
        float m = lg;
        #pragma unroll
        for (int d = 32; d > 0; d >>= 1) m = fmaxf(m, __shfl_xor(m, d));
        if (lane == 0 && wid < 4) wred[wid] = m;
        __syncthreads();
        m = fmaxf(fmaxf(wred[0], wred[1]), fmaxf(wred[2], wred[3]));
        const float pp = (t < NF && t < L) ? __expf(lg - m) : 0.f;
        float s = pp;
        #pragma unroll
        for (int d = 32; d > 0; d >>= 1) s += __shfl_xor(s, d);
        if (lane == 0 && wid < 4) wred[4 + wid] = s;
        __syncthreads();
        s = (wred[4] + wred[5]) + (wred[6] + wred[7]);
        w = pp / s;
      }
      if (t < NF) w_s[t] = w;
      __syncthreads();

      // attended[col] = sum_tok w[tok]*emb[tok][col]; (col, token-group) split
      {
        const int col = t & 63;               // q = wid = token group
        const float* __restrict__ ec = emb_s + wid * 32 * EP + col;
        const float* __restrict__ wp = w_s + wid * 32;
        float a0 = 0.f, a1 = 0.f;
        #pragma unroll
        for (int i = 0; i < 32; i += 2) {
          a0 = fmaf(wp[i],     ec[i * EP],       a0);
          a1 = fmaf(wp[i + 1], ec[(i + 1) * EP], a1);
        }
        red_s[t] = a0 + a1;                   // t == wid*64 + col
      }
      __syncthreads();
      if (t < E) {
        float s0 = 0.f;
        #pragma unroll
        for (int q = 0; q < 8; ++q) s0 += red_s[q * 64 + t];
        att_s[t] = s0;
      }
      __syncthreads();

      // gates: halves — waves 0-3: att@Wih, waves 4-7: qt@Whh
      {
        const int col = t & 255;
        const int hf  = t >> 8;
        const float* __restrict__ W = hf ? Whh : Wih;
        const float* __restrict__ x = hf ? qt_s : att_s;
        float g0 = 0.f, g1 = 0.f, g2 = 0.f, g3 = 0.f;
        #pragma unroll
        for (int e = 0; e < 64; e += 4) {
          const float4 q = *(const float4*)(x + e);
          g0 = fmaf(q.x, W[(e)     * 256 + col], g0);
          g1 = fmaf(q.y, W[(e + 1) * 256 + col], g1);
          g2 = fmaf(q.z, W[(e + 2) * 256 + col], g2);
          g3 = fmaf(q.w, W[(e + 3) * 256 + col], g3);
        }
        red_s[t] = (g0 + g1) + (g2 + g3);
      }
      __syncthreads();
      if (t < 256) red_s[t] = red_s[t] + red_s[256 + t] + bih[t] + bhh[t];
      __syncthreads();
      if (t < H) {
        const float ig = red_s[t];
        const float fg = red_s[H + t];
        const float gg = red_s[2 * H + t];
        const float og = red_s[3 * H + t];
        float c = ct_s[t];
        c = fsig(fg) * c + fsig(ig) * ftanh(gg);
        ct_s[t] = c;
        qt_s[t] = fsig(og) * ftanh(c);
      }
      __syncthreads();
    }
  }

  // ---------------- phase 3: DuelingNet ----------------
  // t1 = relu([att,qt] @ Ws1 + bs1): halves over k
  {
    const int col = t & 255;
    const int hf  = t >> 8;
    const float* __restrict__ x = hf ? qt_s : att_s;
    const float* __restrict__ W = Ws1 + hf * 64 * SHD;
    float x0 = 0.f, x1 = 0.f, x2 = 0.f, x3 = 0.f;
    #pragma unroll
    for (int k = 0; k < 64; k += 4) {
      const float4 q = *(const float4*)(x + k);
      x0 = fmaf(q.x, W[(k)     * SHD + col], x0);
      x1 = fmaf(q.y, W[(k + 1) * SHD + col], x1);
      x2 = fmaf(q.z, W[(k + 2) * SHD + col], x2);
      x3 = fmaf(q.w, W[(k + 3) * SHD + col], x3);
    }
    red_s[t] = (x0 + x1) + (x2 + x3);
  }
  __syncthreads();
  if (t < SHD) t1_s[t] = fmaxf(red_s[t] + red_s[256 + t] + bs1[t], 0.f);
  __syncthreads();
  // sh = relu(t1 @ Ws2 + bs2): quarters over k
  {
    const int col = t & 127;
    const int qq  = t >> 7;
    const float* __restrict__ xq = t1_s + qq * 64;
    float x0 = 0.f, x1 = 0.f, x2 = 0.f, x3 = 0.f;
    #pragma unroll
    for (int k = 0; k < 64; k += 4) {
      const float4 q = *(const float4*)(xq + k);
      x0 = fmaf(q.x, Ws2[(qq * 64 + k)     * SD + col], x0);
      x1 = fmaf(q.y, Ws2[(qq * 64 + k + 1) * SD + col], x1);
      x2 = fmaf(q.z, Ws2[(qq * 64 + k + 2) * SD + col], x2);
      x3 = fmaf(q.w, Ws2[(qq * 64 + k + 3) * SD + col], x3);
    }
    red_s[t] = (x0 + x1) + (x2 + x3);
  }
  __syncthreads();
  if (t < SD)
    sh_s[t] = fmaxf((red_s[t] + red_s[128 + t]) + (red_s[256 + t] + red_s[384 + t]) + bs2[t], 0.f);
  __syncthreads();
  // a1 = relu(sh @ Wp1 + bp1), v1 = relu(sh @ Wv1 + bv1): 2 nets x 2 k-halves
  {
    const int col  = t & 127;
    const int half = (t >> 7) & 1;
    const int net  = t >> 8;
    const float* __restrict__ W  = (net ? Wv1 : Wp1) + half * 64 * SD;
    const float* __restrict__ xh = sh_s + half * 64;
    float x0 = 0.f, x1 = 0.f, x2 = 0.f, x3 = 0.f;
    #pragma unroll
    for (int k = 0; k < 64; k += 4) {
      const float4 q = *(const float4*)(xh + k);
      x0 = fmaf(q.x, W[(k)     * SD + col], x0);
      x1 = fmaf(q.y, W[(k + 1) * SD + col], x1);
      x2 = fmaf(q.z, W[(k + 2) * SD + col], x2);
      x3 = fmaf(q.w, W[(k + 3) * SD + col], x3);
    }
    red_s[t] = (x0 + x1) + (x2 + x3);
  }
  __syncthreads();
  if (t < SD) {
    a1_s[t] = fmaxf(red_s[t] + red_s[128 + t] + bp1[t], 0.f);
  } else if (t < 2 * SD) {
    const int tt = t - SD;
    v1_s[tt] = fmaxf(red_s[256 + tt] + red_s[384 + tt] + bv1[tt], 0.f);
  }
  __syncthreads();
  // v scalar (wave 7, otherwise idle in adv) and adv columns (t < 257)
  if (wid == 7) {
    float vv = fmaf(v1_s[lane], Wv2[lane], v1_s[lane + 64] * Wv2[lane + 64]);
    #pragma unroll
    for (int d = 32; d > 0; d >>= 1) vv += __shfl_xor(vv, d);
    if (lane == 0) v_scalar = vv + bv2[0];
  }
  float adv = 0.f;
  if (t < NA) {
    float x0 = 0.f, x1 = 0.f, x2 = 0.f, x3 = 0.f;
    #pragma unroll
    for (int k = 0; k < SD; k += 4) {
      const float4 a = *(const float4*)(a1_s + k);
      x0 = fmaf(a.x, Wp2[(k)     * NA + t], x0);
      x1 = fmaf(a.y, Wp2[(k + 1) * NA + t], x1);
      x2 = fmaf(a.z, Wp2[(k + 2) * NA + t], x2);
      x3 = fmaf(a.w, Wp2[(k + 3) * NA + t], x3);
    }
    adv = bp2[t] + (x0 + x1) + (x2 + x3);
  }
  float ss = adv;                       // 0 for t >= NA
  #pragma unroll
  for (int d = 32; d > 0; d >>= 1) ss += __shfl_xor(ss, d);
  if (lane == 0) wred[wid] = ss;
  __syncthreads();
  const float mean = ((wred[0] + wred[1]) + (wred[2] + wred[3]) +
                      (wred[4] + wred[5]) + (wred[6] + wred[7])) * (1.f / (float)NA);
  if (t < NA) out[b * NA + t] = v_scalar + adv - mean;
}

}  // namespace

extern "C" void kernel_launch(void* const* d_in, const int* in_sizes, int n_in,
                              void* d_out, int out_size, void* d_ws, size_t ws_size,
                              hipStream_t stream) {
  const float* state    = (const float*)d_in[0];
  const int*   acquired = (const int*)d_in[1];
  const float* We1 = (const float*)d_in[2];
  const float* be1 = (const float*)d_in[3];
  const float* We2 = (const float*)d_in[4];
  const float* be2 = (const float*)d_in[5];
  const float* Wih = (const float*)d_in[6];
  const float* Whh = (const float*)d_in[7];
  const float* bih = (const float*)d_in[8];
  const float* bhh = (const float*)d_in[9];
  const float* Ws1 = (const float*)d_in[10];
  const float* bs1 = (const float*)d_in[11];
  const float* Ws2 = (const float*)d_in[12];
  const float* bs2 = (const float*)d_in[13];
  const float* Wp1 = (const float*)d_in[14];
  const float* bp1 = (const float*)d_in[15];
  const float* Wp2 = (const float*)d_in[16];
  const float* bp2 = (const float*)d_in[17];
  const float* Wv1 = (const float*)d_in[18];
  const float* bv1 = (const float*)d_in[19];
  const float* Wv2 = (const float*)d_in[20];
  const float* bv2 = (const float*)d_in[21];
  float* out = (float*)d_out;

  const int Bn = in_sizes[0] / NF;   // 2048
  hipLaunchKernelGGL(seqnet, dim3(Bn), dim3(512), 0, stream,
                     state, acquired, We1, be1, We2, be2, Wih, Whh, bih, bhh,
                     Ws1, bs1, Ws2, bs2, Wp1, bp1, Wp2, bp2, Wv1, bv1, Wv2, bv2,
                     out);
}

// Round 6
// 435.211 us; speedup vs baseline: 2.6289x; 1.3440x over previous
//
#include <hip/hip_runtime.h>
#include <math.h>

namespace {

constexpr int NF   = 256;   // n_feature / tokens
constexpr int EH   = 128;   // embedder hidden
constexpr int E    = 64;    // embedded dim
constexpr int H    = 64;    // lstm size
constexpr int SHD  = 256;   // shared hidden
constexpr int SD   = 128;   // shared dim
constexpr int NA   = 257;   // n_action
constexpr int NSHUF = 4;

__device__ __forceinline__ float fsig(float x) {
  return 1.f / (1.f + __expf(-x));
}
__device__ __forceinline__ float ftanh(float x) {
  return 1.f - 2.f / (__expf(2.f * x) + 1.f);
}
__device__ __forceinline__ float4 f4ma(float s, const float4 w, float4 a) {
  a.x = fmaf(s, w.x, a.x); a.y = fmaf(s, w.y, a.y);
  a.z = fmaf(s, w.z, a.z); a.w = fmaf(s, w.w, a.w);
  return a;
}

// Allocator lessons (r2-r5): forced min-waves hints -> 64-VGPR budget; no
// hint -> 256. So: design the live set to FIT ~56 regs (8 float4 accums +
// small temps) and request min 4 waves/EU (<=128 cap) as insurance.
__global__ __launch_bounds__(512)
__attribute__((amdgpu_waves_per_eu(4)))
void seqnet(
    const float* __restrict__ state, const int* __restrict__ acquired,
    const float* __restrict__ We1, const float* __restrict__ be1,
    const float* __restrict__ We2, const float* __restrict__ be2,
    const float* __restrict__ Wih, const float* __restrict__ Whh,
    const float* __restrict__ bih, const float* __restrict__ bhh,
    const float* __restrict__ Ws1, const float* __restrict__ bs1,
    const float* __restrict__ Ws2, const float* __restrict__ bs2,
    const float* __restrict__ Wp1, const float* __restrict__ bp1,
    const float* __restrict__ Wp2, const float* __restrict__ bp2,
    const float* __restrict__ Wv1, const float* __restrict__ bv1,
    const float* __restrict__ Wv2, const float* __restrict__ bv2,
    float* __restrict__ out)
{
  const int b    = blockIdx.x;
  const int t    = threadIdx.x;   // 0..511
  const int lane = t & 63;
  const int wid  = t >> 6;        // 0..7

  __shared__ __align__(16) float h_s[32 * NF];     // 32 KB: h K-tile [k][tok]
  __shared__ __align__(16) float we2_s[32 * E];    // 8 KB: We2 K-tile [k][col]
  __shared__ int   id_l[NF];
  __shared__ __align__(16) float val_l[NF];
  __shared__ __align__(16) float w_s[NF];          // logits, then softmax w
  __shared__ __align__(16) float red_s[512];
  __shared__ __align__(16) float partial[8][E];    // per-wave attended partials
  __shared__ __align__(16) float t1_s[SHD];
  __shared__ __align__(16) float sh_s[SD];
  __shared__ __align__(16) float a1_s[SD];
  __shared__ __align__(16) float v1_s[SD];
  __shared__ int   wcnt[4];
  __shared__ float wred[8];
  __shared__ __align__(16) float qt_s[H];
  __shared__ float ct_s[H];
  __shared__ __align__(16) float att_s[E];
  __shared__ float v_scalar;

  // ---------------- phase 0: closed-form "argsort" ----------------
  int ai = 0, pin = 0;
  if (t < NF) {
    id_l[t] = 0; val_l[t] = 0.f;                   // tok >= L: id 0, val 0
    ai = (acquired[b * NF + t] != 0) ? 1 : 0;
    const unsigned long long mask = __ballot(ai);
    pin = __popcll(mask & ((1ull << lane) - 1ull));
    if (lane == 0) wcnt[wid] = __popcll(mask);     // wid 0..3 here
  }
  if (t < H) { qt_s[t] = 0.f; ct_s[t] = 0.f; att_s[t] = 0.f; }
  __syncthreads();
  const int L = wcnt[0] + wcnt[1] + wcnt[2] + wcnt[3];
  if (t < NF && ai) {
    int pexcl = pin;
    #pragma unroll
    for (int w = 0; w < 4; ++w) if (w < wid) pexcl += wcnt[w];
    const int rank = L - pexcl - 1;                // # acquired with index > t
    id_l[rank]  = t + 1;
    val_l[rank] = state[b * NF + t];
  }
  __syncthreads();

  // ---------------- phase 1: embedder as block GEMM ----------------
  // Step A role: thread (p = t>>8, tokA = t&255) computes h[kb..kb+15][tokA].
  // Step B role: thread (tg = t>>4 owns 8 toks, cg = t&15 owns 4 cols).
  const int pA   = t >> 8;
  const int tokA = t & 255;
  const int idA  = id_l[tokA];
  const float vA = val_l[tokA];
  const float* __restrict__ w1r = We1 + idA * EH;
  const int tg8 = (t >> 4) * 8;
  const int cg4 = (t & 15) * 4;

  float4 a0{0,0,0,0}, a1{0,0,0,0}, a2{0,0,0,0}, a3{0,0,0,0};
  float4 a4{0,0,0,0}, a5{0,0,0,0}, a6{0,0,0,0}, a7{0,0,0,0};

  for (int kt = 0; kt < 4; ++kt) {
    // Step A: h tile [32][256]
    {
      const int kb = kt * 32 + pA * 16;
      #pragma unroll
      for (int q = 0; q < 4; ++q) {
        const float4 wr = *(const float4*)(w1r + kb + q * 4);   // per-lane gather
        const float4 w0 = *(const float4*)(We1 + kb + q * 4);   // uniform
        const float4 bb = *(const float4*)(be1 + kb + q * 4);   // uniform
        const int r = (pA * 16 + q * 4) * NF + tokA;
        h_s[r]           = fmaxf(fmaf(vA, w0.x, wr.x) + bb.x, 0.f);
        h_s[r + NF]      = fmaxf(fmaf(vA, w0.y, wr.y) + bb.y, 0.f);
        h_s[r + 2 * NF]  = fmaxf(fmaf(vA, w0.z, wr.z) + bb.z, 0.f);
        h_s[r + 3 * NF]  = fmaxf(fmaf(vA, w0.w, wr.w) + bb.w, 0.f);
      }
      // We2 K-tile slice [32][64]: one float4 per thread
      const int r2 = t >> 4, c2 = (t & 15) * 4;
      *(float4*)&we2_s[r2 * E + c2] = *(const float4*)(We2 + (kt * 32 + r2) * E + c2);
    }
    __syncthreads();
    // Step B: acc[8 tok][4 col] += h[k][tok] * We2[k][col]
    #pragma unroll 4
    for (int k = 0; k < 32; ++k) {
      const float4 w2 = *(const float4*)&we2_s[k * E + cg4];
      const float4 ha = *(const float4*)&h_s[k * NF + tg8];
      const float4 hb = *(const float4*)&h_s[k * NF + tg8 + 4];
      a0 = f4ma(ha.x, w2, a0); a1 = f4ma(ha.y, w2, a1);
      a2 = f4ma(ha.z, w2, a2); a3 = f4ma(ha.w, w2, a3);
      a4 = f4ma(hb.x, w2, a4); a5 = f4ma(hb.y, w2, a5);
      a6 = f4ma(hb.z, w2, a6); a7 = f4ma(hb.w, w2, a7);
    }
    __syncthreads();   // protect h_s/we2_s overwrite next tile
  }
  {  // + be2 (all tokens; masked by w=0 beyond L)
    const float4 b2 = *(const float4*)(be2 + cg4);
    a0.x+=b2.x; a0.y+=b2.y; a0.z+=b2.z; a0.w+=b2.w;
    a1.x+=b2.x; a1.y+=b2.y; a1.z+=b2.z; a1.w+=b2.w;
    a2.x+=b2.x; a2.y+=b2.y; a2.z+=b2.z; a2.w+=b2.w;
    a3.x+=b2.x; a3.y+=b2.y; a3.z+=b2.z; a3.w+=b2.w;
    a4.x+=b2.x; a4.y+=b2.y; a4.z+=b2.z; a4.w+=b2.w;
    a5.x+=b2.x; a5.y+=b2.y; a5.z+=b2.z; a5.w+=b2.w;
    a6.x+=b2.x; a6.y+=b2.y; a6.z+=b2.z; a6.w+=b2.w;
    a7.x+=b2.x; a7.y+=b2.y; a7.z+=b2.z; a7.w+=b2.w;
  }

  // ---------------- phase 2: attention + LSTM ----------------
  if (L > 0) {
    const float invL = 1.f / (float)L;
    for (int it = 0; it < NSHUF; ++it) {
      if (it == 0) {
        // qt == 0 -> masked logits all 0 -> uniform softmax over first L
        if (t < NF) w_s[t] = (t < L) ? invL : 0.f;
        __syncthreads();
      } else {
        // logits: per-token dot(emb, qt); reduce over 16 col-group lanes
        const float4 q4 = *(const float4*)&qt_s[cg4];
        float p0 = fmaf(a0.x,q4.x, fmaf(a0.y,q4.y, fmaf(a0.z,q4.z, a0.w*q4.w)));
        float p1 = fmaf(a1.x,q4.x, fmaf(a1.y,q4.y, fmaf(a1.z,q4.z, a1.w*q4.w)));
        float p2 = fmaf(a2.x,q4.x, fmaf(a2.y,q4.y, fmaf(a2.z,q4.z, a2.w*q4.w)));
        float p3 = fmaf(a3.x,q4.x, fmaf(a3.y,q4.y, fmaf(a3.z,q4.z, a3.w*q4.w)));
        float p4 = fmaf(a4.x,q4.x, fmaf(a4.y,q4.y, fmaf(a4.z,q4.z, a4.w*q4.w)));
        float p5 = fmaf(a5.x,q4.x, fmaf(a5.y,q4.y, fmaf(a5.z,q4.z, a5.w*q4.w)));
        float p6 = fmaf(a6.x,q4.x, fmaf(a6.y,q4.y, fmaf(a6.z,q4.z, a6.w*q4.w)));
        float p7 = fmaf(a7.x,q4.x, fmaf(a7.y,q4.y, fmaf(a7.z,q4.z, a7.w*q4.w)));
        #pragma unroll
        for (int d = 1; d <= 8; d <<= 1) {
          p0 += __shfl_xor(p0, d); p1 += __shfl_xor(p1, d);
          p2 += __shfl_xor(p2, d); p3 += __shfl_xor(p3, d);
          p4 += __shfl_xor(p4, d); p5 += __shfl_xor(p5, d);
          p6 += __shfl_xor(p6, d); p7 += __shfl_xor(p7, d);
        }
        if ((t & 15) == 0) {
          w_s[tg8]     = p0; w_s[tg8 + 1] = p1;
          w_s[tg8 + 2] = p2; w_s[tg8 + 3] = p3;
          w_s[tg8 + 4] = p4; w_s[tg8 + 5] = p5;
          w_s[tg8 + 6] = p6; w_s[tg8 + 7] = p7;
        }
        __syncthreads();
        // softmax over 256 logits (first 256 threads), in-place into w_s
        float lg = -1e30f;
        if (t < NF && t < L) lg = w_s[t];
        float m = lg;
        #pragma unroll
        for (int d = 32; d > 0; d >>= 1) m = fmaxf(m, __shfl_xor(m, d));
        if (lane == 0 && wid < 4) wred[wid] = m;
        __syncthreads();
        m = fmaxf(fmaxf(wred[0], wred[1]), fmaxf(wred[2], wred[3]));
        const float pp = (t < NF && t < L) ? __expf(lg - m) : 0.f;
        float s = pp;
        #pragma unroll
        for (int d = 32; d > 0; d >>= 1) s += __shfl_xor(s, d);
        if (lane == 0 && wid < 4) wred[4 + wid] = s;
        __syncthreads();
        s = (wred[4] + wred[5]) + (wred[6] + wred[7]);
        if (t < NF) w_s[t] = pp / s;
        __syncthreads();
      }

      // attended[col] = sum_tok w[tok]*emb[tok][col] from registers
      {
        const float4 wv0 = *(const float4*)&w_s[tg8];
        const float4 wv1 = *(const float4*)&w_s[tg8 + 4];
        float4 ap{0,0,0,0};
        ap = f4ma(wv0.x, a0, ap); ap = f4ma(wv0.y, a1, ap);
        ap = f4ma(wv0.z, a2, ap); ap = f4ma(wv0.w, a3, ap);
        ap = f4ma(wv1.x, a4, ap); ap = f4ma(wv1.y, a5, ap);
        ap = f4ma(wv1.z, a6, ap); ap = f4ma(wv1.w, a7, ap);
        #pragma unroll
        for (int d = 16; d <= 32; d <<= 1) {
          ap.x += __shfl_xor(ap.x, d); ap.y += __shfl_xor(ap.y, d);
          ap.z += __shfl_xor(ap.z, d); ap.w += __shfl_xor(ap.w, d);
        }
        if (lane < 16) *(float4*)&partial[wid][cg4] = ap;
      }
      __syncthreads();
      if (t < E) {
        float s0 = 0.f;
        #pragma unroll
        for (int q = 0; q < 8; ++q) s0 += partial[q][t];
        att_s[t] = s0;
      }
      __syncthreads();

      // gates: waves 0-3: att@Wih, waves 4-7: qt@Whh (qt=0 at it0 -> 0)
      {
        const int col = t & 255;
        const int hf  = t >> 8;
        const float* __restrict__ W = hf ? Whh : Wih;
        const float* __restrict__ x = hf ? qt_s : att_s;
        float g0 = 0.f, g1 = 0.f, g2 = 0.f, g3 = 0.f;
        #pragma unroll
        for (int e = 0; e < 64; e += 4) {
          const float4 q = *(const float4*)(x + e);
          g0 = fmaf(q.x, W[(e)     * 256 + col], g0);
          g1 = fmaf(q.y, W[(e + 1) * 256 + col], g1);
          g2 = fmaf(q.z, W[(e + 2) * 256 + col], g2);
          g3 = fmaf(q.w, W[(e + 3) * 256 + col], g3);
        }
        red_s[t] = (g0 + g1) + (g2 + g3);
      }
      __syncthreads();
      if (t < 256) red_s[t] = red_s[t] + red_s[256 + t] + bih[t] + bhh[t];
      __syncthreads();
      if (t < H) {
        const float ig = red_s[t];
        const float fg = red_s[H + t];
        const float gg = red_s[2 * H + t];
        const float og = red_s[3 * H + t];
        float c = ct_s[t];
        c = fsig(fg) * c + fsig(ig) * ftanh(gg);
        ct_s[t] = c;
        qt_s[t] = fsig(og) * ftanh(c);
      }
      __syncthreads();
    }
  }

  // ---------------- phase 3: DuelingNet ----------------
  {
    const int col = t & 255;
    const int hf  = t >> 8;
    const float* __restrict__ x = hf ? qt_s : att_s;
    const float* __restrict__ W = Ws1 + hf * 64 * SHD;
    float x0 = 0.f, x1 = 0.f, x2 = 0.f, x3 = 0.f;
    #pragma unroll
    for (int k = 0; k < 64; k += 4) {
      const float4 q = *(const float4*)(x + k);
      x0 = fmaf(q.x, W[(k)     * SHD + col], x0);
      x1 = fmaf(q.y, W[(k + 1) * SHD + col], x1);
      x2 = fmaf(q.z, W[(k + 2) * SHD + col], x2);
      x3 = fmaf(q.w, W[(k + 3) * SHD + col], x3);
    }
    red_s[t] = (x0 + x1) + (x2 + x3);
  }
  __syncthreads();
  if (t < SHD) t1_s[t] = fmaxf(red_s[t] + red_s[256 + t] + bs1[t], 0.f);
  __syncthreads();
  {
    const int col = t & 127;
    const int qq  = t >> 7;
    const float* __restrict__ xq = t1_s + qq * 64;
    float x0 = 0.f, x1 = 0.f, x2 = 0.f, x3 = 0.f;
    #pragma unroll
    for (int k = 0; k < 64; k += 4) {
      const float4 q = *(const float4*)(xq + k);
      x0 = fmaf(q.x, Ws2[(qq * 64 + k)     * SD + col], x0);
      x1 = fmaf(q.y, Ws2[(qq * 64 + k + 1) * SD + col], x1);
      x2 = fmaf(q.z, Ws2[(qq * 64 + k + 2) * SD + col], x2);
      x3 = fmaf(q.w, Ws2[(qq * 64 + k + 3) * SD + col], x3);
    }
    red_s[t] = (x0 + x1) + (x2 + x3);
  }
  __syncthreads();
  if (t < SD)
    sh_s[t] = fmaxf((red_s[t] + red_s[128 + t]) + (red_s[256 + t] + red_s[384 + t]) + bs2[t], 0.f);
  __syncthreads();
  {
    const int col  = t & 127;
    const int half = (t >> 7) & 1;
    const int net  = t >> 8;
    const float* __restrict__ W  = (net ? Wv1 : Wp1) + half * 64 * SD;
    const float* __restrict__ xh = sh_s + half * 64;
    float x0 = 0.f, x1 = 0.f, x2 = 0.f, x3 = 0.f;
    #pragma unroll
    for (int k = 0; k < 64; k += 4) {
      const float4 q = *(const float4*)(xh + k);
      x0 = fmaf(q.x, W[(k)     * SD + col], x0);
      x1 = fmaf(q.y, W[(k + 1) * SD + col], x1);
      x2 = fmaf(q.z, W[(k + 2) * SD + col], x2);
      x3 = fmaf(q.w, W[(k + 3) * SD + col], x3);
    }
    red_s[t] = (x0 + x1) + (x2 + x3);
  }
  __syncthreads();
  if (t < SD) {
    a1_s[t] = fmaxf(red_s[t] + red_s[128 + t] + bp1[t], 0.f);
  } else if (t < 2 * SD) {
    const int tt = t - SD;
    v1_s[tt] = fmaxf(red_s[256 + tt] + red_s[384 + tt] + bv1[tt], 0.f);
  }
  __syncthreads();
  if (wid == 7) {
    float vv = fmaf(v1_s[lane], Wv2[lane], v1_s[lane + 64] * Wv2[lane + 64]);
    #pragma unroll
    for (int d = 32; d > 0; d >>= 1) vv += __shfl_xor(vv, d);
    if (lane == 0) v_scalar = vv + bv2[0];
  }
  float adv = 0.f;
  if (t < NA) {
    float x0 = 0.f, x1 = 0.f, x2 = 0.f, x3 = 0.f;
    #pragma unroll
    for (int k = 0; k < SD; k += 4) {
      const float4 a = *(const float4*)(a1_s + k);
      x0 = fmaf(a.x, Wp2[(k)     * NA + t], x0);
      x1 = fmaf(a.y, Wp2[(k + 1) * NA + t], x1);
      x2 = fmaf(a.z, Wp2[(k + 2) * NA + t], x2);
      x3 = fmaf(a.w, Wp2[(k + 3) * NA + t], x3);
    }
    adv = bp2[t] + (x0 + x1) + (x2 + x3);
  }
  float ss = adv;                       // 0 for t >= NA
  #pragma unroll
  for (int d = 32; d > 0; d >>= 1) ss += __shfl_xor(ss, d);
  if (lane == 0) wred[wid] = ss;
  __syncthreads();
  const float mean = ((wred[0] + wred[1]) + (wred[2] + wred[3]) +
                      (wred[4] + wred[5]) + (wred[6] + wred[7])) * (1.f / (float)NA);
  if (t < NA) out[b * NA + t] = v_scalar + adv - mean;
}

}  // namespace

extern "C" void kernel_launch(void* const* d_in, const int* in_sizes, int n_in,
                              void* d_out, int out_size, void* d_ws, size_t ws_size,
                              hipStream_t stream) {
  const float* state    = (const float*)d_in[0];
  const int*   acquired = (const int*)d_in[1];
  const float* We1 = (const float*)d_in[2];
  const float* be1 = (const float*)d_in[3];
  const float* We2 = (const float*)d_in[4];
  const float* be2 = (const float*)d_in[5];
  const float* Wih = (const float*)d_in[6];
  const float* Whh = (const float*)d_in[7];
  const float* bih = (const float*)d_in[8];
  const float* bhh = (const float*)d_in[9];
  const float* Ws1 = (const float*)d_in[10];
  const float* bs1 = (const float*)d_in[11];
  const float* Ws2 = (const float*)d_in[12];
  const float* bs2 = (const float*)d_in[13];
  const float* Wp1 = (const float*)d_in[14];
  const float* bp1 = (const float*)d_in[15];
  const float* Wp2 = (const float*)d_in[16];
  const float* bp2 = (const float*)d_in[17];
  const float* Wv1 = (const float*)d_in[18];
  const float* bv1 = (const float*)d_in[19];
  const float* Wv2 = (const float*)d_in[20];
  const float* bv2 = (const float*)d_in[21];
  float* out = (float*)d_out;

  const int Bn = in_sizes[0] / NF;   // 2048
  hipLaunchKernelGGL(seqnet, dim3(Bn), dim3(512), 0, stream,
                     state, acquired, We1, be1, We2, be2, Wih, Whh, bih, bhh,
                     Ws1, bs1, Ws2, bs2, Wp1, bp1, Wp2, bp2, Wv1, bv1, Wv2, bv2,
                     out);
}

// Round 7
// 294.865 us; speedup vs baseline: 3.8801x; 1.4760x over previous
//
#include <hip/hip_runtime.h>
#include <math.h>

namespace {

constexpr int NF   = 256;   // n_feature / tokens
constexpr int EH   = 128;   // embedder hidden
constexpr int E    = 64;    // embedded dim
constexpr int EP   = 65;    // padded emb row stride (odd => conflict-free)
constexpr int H    = 64;    // lstm size
constexpr int SHD  = 256;   // shared hidden
constexpr int SD   = 128;   // shared dim
constexpr int NA   = 257;   // n_action
constexpr int NSHUF = 4;

__device__ __forceinline__ float fsig(float x) {
  return 1.f / (1.f + __expf(-x));
}
__device__ __forceinline__ float ftanh(float x) {
  return 1.f - 2.f / (__expf(2.f * x) + 1.f);
}
__device__ __forceinline__ float4 f4ma(float s, const float4 w, float4 a) {
  a.x = fmaf(s, w.x, a.x); a.y = fmaf(s, w.y, a.y);
  a.z = fmaf(s, w.z, a.z); a.w = fmaf(s, w.w, a.w);
  return a;
}

// r6 lesson: emb accumulators must DIE after the embedder (spill-free at the
// 64-VGPR budget); emb lives in padded LDS for phase 2 (r5-verified layout).
__global__ __launch_bounds__(512)
__attribute__((amdgpu_waves_per_eu(4)))
void seqnet(
    const float* __restrict__ state, const int* __restrict__ acquired,
    const float* __restrict__ We1, const float* __restrict__ be1,
    const float* __restrict__ We2, const float* __restrict__ be2,
    const float* __restrict__ Wih, const float* __restrict__ Whh,
    const float* __restrict__ bih, const float* __restrict__ bhh,
    const float* __restrict__ Ws1, const float* __restrict__ bs1,
    const float* __restrict__ Ws2, const float* __restrict__ bs2,
    const float* __restrict__ Wp1, const float* __restrict__ bp1,
    const float* __restrict__ Wp2, const float* __restrict__ bp2,
    const float* __restrict__ Wv1, const float* __restrict__ bv1,
    const float* __restrict__ Wv2, const float* __restrict__ bv2,
    float* __restrict__ out)
{
  const int b    = blockIdx.x;
  const int t    = threadIdx.x;   // 0..511
  const int lane = t & 63;
  const int wid  = t >> 6;        // 0..7

  // big: embedder phase = h_s[32][256] (32KB) | we2_s[32][64] (8KB);
  //      afterwards     = emb[256][EP] fp32 (66.56 KB).
  __shared__ __align__(16) float big[NF * EP];
  __shared__ int   id_l[NF];
  __shared__ __align__(16) float val_l[NF];
  __shared__ __align__(16) float w_s[NF];
  __shared__ __align__(16) float red_s[512];
  __shared__ __align__(16) float partial[8][E];
  __shared__ __align__(16) float t1_s[SHD];
  __shared__ __align__(16) float sh_s[SD];
  __shared__ __align__(16) float a1_s[SD];
  __shared__ __align__(16) float v1_s[SD];
  __shared__ int   wcnt[4];
  __shared__ float wred[8];
  __shared__ __align__(16) float qt_s[H];
  __shared__ float ct_s[H];
  __shared__ __align__(16) float att_s[E];
  __shared__ float v_scalar;

  // ---------------- phase 0: closed-form "argsort" ----------------
  int ai = 0, pin = 0;
  if (t < NF) {
    id_l[t] = 0; val_l[t] = 0.f;                   // tok >= L defaults
    ai = (acquired[b * NF + t] != 0) ? 1 : 0;
    const unsigned long long mask = __ballot(ai);
    pin = __popcll(mask & ((1ull << lane) - 1ull));
    if (lane == 0) wcnt[wid] = __popcll(mask);     // wid 0..3 here
  }
  if (t < H) { qt_s[t] = 0.f; ct_s[t] = 0.f; att_s[t] = 0.f; }
  __syncthreads();
  const int L = wcnt[0] + wcnt[1] + wcnt[2] + wcnt[3];
  if (t < NF && ai) {
    int pexcl = pin;
    #pragma unroll
    for (int w = 0; w < 4; ++w) if (w < wid) pexcl += wcnt[w];
    const int rank = L - pexcl - 1;                // # acquired with index > t
    id_l[rank]  = t + 1;
    val_l[rank] = state[b * NF + t];
  }
  __syncthreads();

  // ---------------- phase 1: embedder as block GEMM ----------------
  float* __restrict__ h_s   = big;            // [32][256]
  float* __restrict__ we2_s = big + 32 * NF;  // [32][64]
  const int pA   = t >> 8;
  const int tokA = t & 255;
  const int idA  = id_l[tokA];
  const float vA = val_l[tokA];
  const float* __restrict__ w1r = We1 + idA * EH;
  const int tg8 = (t >> 4) * 8;               // 8 tokens owned in step B
  const int cg4 = (t & 15) * 4;               // 4 cols owned in step B

  float4 a0{0,0,0,0}, a1{0,0,0,0}, a2{0,0,0,0}, a3{0,0,0,0};
  float4 a4{0,0,0,0}, a5{0,0,0,0}, a6{0,0,0,0}, a7{0,0,0,0};

  for (int kt = 0; kt < 4; ++kt) {
    {  // step A: h K-tile [32][256] (all tokens: cheap, keeps h defined)
      const int kb = kt * 32 + pA * 16;
      #pragma unroll
      for (int q = 0; q < 4; ++q) {
        const float4 wr = *(const float4*)(w1r + kb + q * 4);   // gather
        const float4 w0 = *(const float4*)(We1 + kb + q * 4);   // uniform
        const float4 bb = *(const float4*)(be1 + kb + q * 4);   // uniform
        const int r = (pA * 16 + q * 4) * NF + tokA;
        h_s[r]          = fmaxf(fmaf(vA, w0.x, wr.x) + bb.x, 0.f);
        h_s[r + NF]     = fmaxf(fmaf(vA, w0.y, wr.y) + bb.y, 0.f);
        h_s[r + 2*NF]   = fmaxf(fmaf(vA, w0.z, wr.z) + bb.z, 0.f);
        h_s[r + 3*NF]   = fmaxf(fmaf(vA, w0.w, wr.w) + bb.w, 0.f);
      }
      const int r2 = t >> 4, c2 = (t & 15) * 4;
      *(float4*)&we2_s[r2 * E + c2] = *(const float4*)(We2 + (kt * 32 + r2) * E + c2);
    }
    __syncthreads();
    if (tg8 < L) {   // wave-mostly-uniform skip of dead tokens
      #pragma unroll 2
      for (int k = 0; k < 32; ++k) {
        const float4 w2 = *(const float4*)&we2_s[k * E + cg4];
        const float4 ha = *(const float4*)&h_s[k * NF + tg8];
        a0 = f4ma(ha.x, w2, a0); a1 = f4ma(ha.y, w2, a1);
        a2 = f4ma(ha.z, w2, a2); a3 = f4ma(ha.w, w2, a3);
        const float4 hb = *(const float4*)&h_s[k * NF + tg8 + 4];
        a4 = f4ma(hb.x, w2, a4); a5 = f4ma(hb.y, w2, a5);
        a6 = f4ma(hb.z, w2, a6); a7 = f4ma(hb.w, w2, a7);
      }
    }
    __syncthreads();   // protect h_s/we2_s overwrite (or emb overlay below)
  }
  {  // retire accumulators into padded LDS emb (scalar stores: no align UB)
    const float4 b2 = *(const float4*)(be2 + cg4);
    float* e0 = &big[tg8 * EP + cg4];
    e0[0]=a0.x+b2.x; e0[1]=a0.y+b2.y; e0[2]=a0.z+b2.z; e0[3]=a0.w+b2.w; e0+=EP;
    e0[0]=a1.x+b2.x; e0[1]=a1.y+b2.y; e0[2]=a1.z+b2.z; e0[3]=a1.w+b2.w; e0+=EP;
    e0[0]=a2.x+b2.x; e0[1]=a2.y+b2.y; e0[2]=a2.z+b2.z; e0[3]=a2.w+b2.w; e0+=EP;
    e0[0]=a3.x+b2.x; e0[1]=a3.y+b2.y; e0[2]=a3.z+b2.z; e0[3]=a3.w+b2.w; e0+=EP;
    e0[0]=a4.x+b2.x; e0[1]=a4.y+b2.y; e0[2]=a4.z+b2.z; e0[3]=a4.w+b2.w; e0+=EP;
    e0[0]=a5.x+b2.x; e0[1]=a5.y+b2.y; e0[2]=a5.z+b2.z; e0[3]=a5.w+b2.w; e0+=EP;
    e0[0]=a6.x+b2.x; e0[1]=a6.y+b2.y; e0[2]=a6.z+b2.z; e0[3]=a6.w+b2.w; e0+=EP;
    e0[0]=a7.x+b2.x; e0[1]=a7.y+b2.y; e0[2]=a7.z+b2.z; e0[3]=a7.w+b2.w;
  }
  __syncthreads();

  // ---------------- phase 2: attention + LSTM (emb in LDS) ----------------
  if (L > 0) {
    const float invL = 1.f / (float)L;
    for (int it = 0; it < NSHUF; ++it) {
      if (it == 0) {
        // qt == 0 -> masked logits all 0 -> uniform softmax over first L
        if (t < NF) w_s[t] = (t < L) ? invL : 0.f;
        __syncthreads();
      } else {
        float lg = -1e30f;
        if (t < L) {
          float d0 = 0.f, d1 = 0.f, d2 = 0.f, d3 = 0.f;
          const float* __restrict__ er = big + t * EP;
          #pragma unroll
          for (int j = 0; j < E; j += 4) {
            const float4 q = *(const float4*)(qt_s + j);
            d0 = fmaf(er[j],     q.x, d0);
            d1 = fmaf(er[j + 1], q.y, d1);
            d2 = fmaf(er[j + 2], q.z, d2);
            d3 = fmaf(er[j + 3], q.w, d3);
          }
          lg = (d0 + d1) + (d2 + d3);
        }
        float m = lg;
        #pragma unroll
        for (int d = 32; d > 0; d >>= 1) m = fmaxf(m, __shfl_xor(m, d));
        if (lane == 0 && wid < 4) wred[wid] = m;
        __syncthreads();
        m = fmaxf(fmaxf(wred[0], wred[1]), fmaxf(wred[2], wred[3]));
        const float pp = (t < L) ? __expf(lg - m) : 0.f;
        float s = pp;
        #pragma unroll
        for (int d = 32; d > 0; d >>= 1) s += __shfl_xor(s, d);
        if (lane == 0 && wid < 4) wred[4 + wid] = s;
        __syncthreads();
        s = (wred[4] + wred[5]) + (wred[6] + wred[7]);
        if (t < NF) w_s[t] = pp / s;
        __syncthreads();
      }

      // attended[col] = sum_tok w[tok]*emb[tok][col]; (col, token-group)
      {
        const int col = t & 63;               // token group = wid
        if (wid * 32 < L) {
          const float* __restrict__ ec = big + wid * 32 * EP + col;
          const float* __restrict__ wp = w_s + wid * 32;
          float c0 = 0.f, c1 = 0.f;
          #pragma unroll
          for (int i = 0; i < 32; i += 2) {
            c0 = fmaf(wp[i],     ec[i * EP],       c0);
            c1 = fmaf(wp[i + 1], ec[(i + 1) * EP], c1);
          }
          red_s[t] = c0 + c1;
        } else {
          red_s[t] = 0.f;
        }
      }
      __syncthreads();
      if (t < E) {
        float s0 = 0.f;
        #pragma unroll
        for (int q = 0; q < 8; ++q) s0 += red_s[q * 64 + t];
        att_s[t] = s0;
      }
      __syncthreads();

      // gates: waves 0-3: att@Wih, waves 4-7: qt@Whh (qt=0 at it0 -> 0)
      {
        const int col = t & 255;
        const int hf  = t >> 8;
        const float* __restrict__ W = hf ? Whh : Wih;
        const float* __restrict__ x = hf ? qt_s : att_s;
        float g0 = 0.f, g1 = 0.f, g2 = 0.f, g3 = 0.f;
        #pragma unroll
        for (int e = 0; e < 64; e += 4) {
          const float4 q = *(const float4*)(x + e);
          g0 = fmaf(q.x, W[(e)     * 256 + col], g0);
          g1 = fmaf(q.y, W[(e + 1) * 256 + col], g1);
          g2 = fmaf(q.z, W[(e + 2) * 256 + col], g2);
          g3 = fmaf(q.w, W[(e + 3) * 256 + col], g3);
        }
        red_s[t] = (g0 + g1) + (g2 + g3);
      }
      __syncthreads();
      if (t < 256) red_s[t] = red_s[t] + red_s[256 + t] + bih[t] + bhh[t];
      __syncthreads();
      if (t < H) {
        const float ig = red_s[t];
        const float fg = red_s[H + t];
        const float gg = red_s[2 * H + t];
        const float og = red_s[3 * H + t];
        float c = ct_s[t];
        c = fsig(fg) * c + fsig(ig) * ftanh(gg);
        ct_s[t] = c;
        qt_s[t] = fsig(og) * ftanh(c);
      }
      __syncthreads();
    }
  }

  // ---------------- phase 3: DuelingNet ----------------
  {
    const int col = t & 255;
    const int hf  = t >> 8;
    const float* __restrict__ x = hf ? qt_s : att_s;
    const float* __restrict__ W = Ws1 + hf * 64 * SHD;
    float x0 = 0.f, x1 = 0.f, x2 = 0.f, x3 = 0.f;
    #pragma unroll
    for (int k = 0; k < 64; k += 4) {
      const float4 q = *(const float4*)(x + k);
      x0 = fmaf(q.x, W[(k)     * SHD + col], x0);
      x1 = fmaf(q.y, W[(k + 1) * SHD + col], x1);
      x2 = fmaf(q.z, W[(k + 2) * SHD + col], x2);
      x3 = fmaf(q.w, W[(k + 3) * SHD + col], x3);
    }
    red_s[t] = (x0 + x1) + (x2 + x3);
  }
  __syncthreads();
  if (t < SHD) t1_s[t] = fmaxf(red_s[t] + red_s[256 + t] + bs1[t], 0.f);
  __syncthreads();
  {
    const int col = t & 127;
    const int qq  = t >> 7;
    const float* __restrict__ xq = t1_s + qq * 64;
    float x0 = 0.f, x1 = 0.f, x2 = 0.f, x3 = 0.f;
    #pragma unroll
    for (int k = 0; k < 64; k += 4) {
      const float4 q = *(const float4*)(xq + k);
      x0 = fmaf(q.x, Ws2[(qq * 64 + k)     * SD + col], x0);
      x1 = fmaf(q.y, Ws2[(qq * 64 + k + 1) * SD + col], x1);
      x2 = fmaf(q.z, Ws2[(qq * 64 + k + 2) * SD + col], x2);
      x3 = fmaf(q.w, Ws2[(qq * 64 + k + 3) * SD + col], x3);
    }
    red_s[t] = (x0 + x1) + (x2 + x3);
  }
  __syncthreads();
  if (t < SD)
    sh_s[t] = fmaxf((red_s[t] + red_s[128 + t]) + (red_s[256 + t] + red_s[384 + t]) + bs2[t], 0.f);
  __syncthreads();
  {
    const int col  = t & 127;
    const int half = (t >> 7) & 1;
    const int net  = t >> 8;
    const float* __restrict__ W  = (net ? Wv1 : Wp1) + half * 64 * SD;
    const float* __restrict__ xh = sh_s + half * 64;
    float x0 = 0.f, x1 = 0.f, x2 = 0.f, x3 = 0.f;
    #pragma unroll
    for (int k = 0; k < 64; k += 4) {
      const float4 q = *(const float4*)(xh + k);
      x0 = fmaf(q.x, W[(k)     * SD + col], x0);
      x1 = fmaf(q.y, W[(k + 1) * SD + col], x1);
      x2 = fmaf(q.z, W[(k + 2) * SD + col], x2);
      x3 = fmaf(q.w, W[(k + 3) * SD + col], x3);
    }
    red_s[t] = (x0 + x1) + (x2 + x3);
  }
  __syncthreads();
  if (t < SD) {
    a1_s[t] = fmaxf(red_s[t] + red_s[128 + t] + bp1[t], 0.f);
  } else if (t < 2 * SD) {
    const int tt = t - SD;
    v1_s[tt] = fmaxf(red_s[256 + tt] + red_s[384 + tt] + bv1[tt], 0.f);
  }
  __syncthreads();
  if (wid == 7) {
    float vv = fmaf(v1_s[lane], Wv2[lane], v1_s[lane + 64] * Wv2[lane + 64]);
    #pragma unroll
    for (int d = 32; d > 0; d >>= 1) vv += __shfl_xor(vv, d);
    if (lane == 0) v_scalar = vv + bv2[0];
  }
  float adv = 0.f;
  if (t < NA) {
    float x0 = 0.f, x1 = 0.f, x2 = 0.f, x3 = 0.f;
    #pragma unroll
    for (int k = 0; k < SD; k += 4) {
      const float4 a = *(const float4*)(a1_s + k);
      x0 = fmaf(a.x, Wp2[(k)     * NA + t], x0);
      x1 = fmaf(a.y, Wp2[(k + 1) * NA + t], x1);
      x2 = fmaf(a.z, Wp2[(k + 2) * NA + t], x2);
      x3 = fmaf(a.w, Wp2[(k + 3) * NA + t], x3);
    }
    adv = bp2[t] + (x0 + x1) + (x2 + x3);
  }
  float ss = adv;                       // 0 for t >= NA
  #pragma unroll
  for (int d = 32; d > 0; d >>= 1) ss += __shfl_xor(ss, d);
  if (lane == 0) wred[wid] = ss;
  __syncthreads();
  const float mean = ((wred[0] + wred[1]) + (wred[2] + wred[3]) +
                      (wred[4] + wred[5]) + (wred[6] + wred[7])) * (1.f / (float)NA);
  if (t < NA) out[b * NA + t] = v_scalar + adv - mean;
}

}  // namespace

extern "C" void kernel_launch(void* const* d_in, const int* in_sizes, int n_in,
                              void* d_out, int out_size, void* d_ws, size_t ws_size,
                              hipStream_t stream) {
  const float* state    = (const float*)d_in[0];
  const int*   acquired = (const int*)d_in[1];
  const float* We1 = (const float*)d_in[2];
  const float* be1 = (const float*)d_in[3];
  const float* We2 = (const float*)d_in[4];
  const float* be2 = (const float*)d_in[5];
  const float* Wih = (const float*)d_in[6];
  const float* Whh = (const float*)d_in[7];
  const float* bih = (const float*)d_in[8];
  const float* bhh = (const float*)d_in[9];
  const float* Ws1 = (const float*)d_in[10];
  const float* bs1 = (const float*)d_in[11];
  const float* Ws2 = (const float*)d_in[12];
  const float* bs2 = (const float*)d_in[13];
  const float* Wp1 = (const float*)d_in[14];
  const float* bp1 = (const float*)d_in[15];
  const float* Wp2 = (const float*)d_in[16];
  const float* bp2 = (const float*)d_in[17];
  const float* Wv1 = (const float*)d_in[18];
  const float* bv1 = (const float*)d_in[19];
  const float* Wv2 = (const float*)d_in[20];
  const float* bv2 = (const float*)d_in[21];
  float* out = (float*)d_out;

  const int Bn = in_sizes[0] / NF;   // 2048
  hipLaunchKernelGGL(seqnet, dim3(Bn), dim3(512), 0, stream,
                     state, acquired, We1, be1, We2, be2, Wih, Whh, bih, bhh,
                     Ws1, bs1, Ws2, bs2, Wp1, bp1, Wp2, bp2, Wv1, bv1, Wv2, bv2,
                     out);
}